// Round 1
// baseline (1767.683 us; speedup 1.0000x reference)
//
#include <hip/hip_runtime.h>
#include <math.h>

#define BATCH   8
#define SEQ     4096
#define DMODEL  256
#define DINNER  512
#define DSTATE  64
#define NHEADS  8
#define CONVDIM 640          // DINNER + 2*DSTATE
#define DPROJ   1160         // 2*DINNER + 2*DSTATE + NHEADS
#define NROWS   (BATCH*SEQ)  // 32768

// ---- static workspace (BSS, allocated at module load; ws_size-independent) ----
__device__ float g_xn[(size_t)NROWS * DMODEL];    //  33.5 MB
__device__ float g_zx[(size_t)NROWS * DPROJ];     // 152.0 MB
__device__ float g_conv[(size_t)NROWS * CONVDIM]; //  83.9 MB (x part overwritten by y in scan)
__device__ float g_yzn[(size_t)NROWS * DINNER];   //  67.1 MB

// ---------------- kernel 1: rmsnorm of x (D=256), one wave per row ----------------
__global__ __launch_bounds__(256) void rmsnorm_x_kernel(const float* __restrict__ x,
                                                        const float* __restrict__ w,
                                                        float* __restrict__ xn) {
    const int row  = blockIdx.x * 4 + (threadIdx.x >> 6);
    const int lane = threadIdx.x & 63;
    const float4 v = *(const float4*)(x + (size_t)row * DMODEL + lane * 4);
    float ss = v.x * v.x + v.y * v.y + v.z * v.z + v.w * v.w;
#pragma unroll
    for (int off = 1; off < 64; off <<= 1) ss += __shfl_xor(ss, off);
    const float rs = rsqrtf(ss * (1.0f / DMODEL) + 1.1920929e-7f);
    const float4 wv = *(const float4*)(w + lane * 4);
    float4 o;
    o.x = v.x * rs * wv.x; o.y = v.y * rs * wv.y;
    o.z = v.z * rs * wv.z; o.w = v.w * rs * wv.w;
    *(float4*)(xn + (size_t)row * DMODEL + lane * 4) = o;
}

// ---------------- fp32 SIMT GEMM: C[M][N] = A[M][K] * B[N][K]^T (+ optional residual) ----
// BM=BN=128, BK=16, 256 threads, 8x8 micro-tile. M%128==0, K%16==0 assumed; N guarded.
template <bool RES>
__global__ __launch_bounds__(256) void gemm_nt(const float* __restrict__ A,
                                               const float* __restrict__ B,
                                               const float* __restrict__ R,
                                               float* __restrict__ C,
                                               int M, int N, int K) {
    __shared__ float As[16][132];
    __shared__ float Bs[16][132];
    const int tid = threadIdx.x;
    const int tx = tid & 15, ty = tid >> 4;
    const int m0 = blockIdx.y * 128, n0 = blockIdx.x * 128;

    float acc[8][8];
#pragma unroll
    for (int i = 0; i < 8; ++i)
#pragma unroll
        for (int j = 0; j < 8; ++j) acc[i][j] = 0.f;

    for (int k0 = 0; k0 < K; k0 += 16) {
#pragma unroll
        for (int r = 0; r < 2; ++r) {
            const int idx = tid + r * 256;       // 0..511
            const int mm  = idx >> 2;            // 0..127
            const int k4  = (idx & 3) << 2;      // 0,4,8,12
            const float4 va = *(const float4*)(A + (size_t)(m0 + mm) * K + (k0 + k4));
            As[k4 + 0][mm] = va.x; As[k4 + 1][mm] = va.y;
            As[k4 + 2][mm] = va.z; As[k4 + 3][mm] = va.w;
            float4 vb = make_float4(0.f, 0.f, 0.f, 0.f);
            if (n0 + mm < N) vb = *(const float4*)(B + (size_t)(n0 + mm) * K + (k0 + k4));
            Bs[k4 + 0][mm] = vb.x; Bs[k4 + 1][mm] = vb.y;
            Bs[k4 + 2][mm] = vb.z; Bs[k4 + 3][mm] = vb.w;
        }
        __syncthreads();
#pragma unroll
        for (int kk = 0; kk < 16; ++kk) {
            float a[8], b[8];
            *(float4*)&a[0] = *(const float4*)&As[kk][ty * 8];
            *(float4*)&a[4] = *(const float4*)&As[kk][ty * 8 + 4];
            *(float4*)&b[0] = *(const float4*)&Bs[kk][tx * 8];
            *(float4*)&b[4] = *(const float4*)&Bs[kk][tx * 8 + 4];
#pragma unroll
            for (int i = 0; i < 8; ++i)
#pragma unroll
                for (int j = 0; j < 8; ++j) acc[i][j] = fmaf(a[i], b[j], acc[i][j]);
        }
        __syncthreads();
    }
#pragma unroll
    for (int i = 0; i < 8; ++i) {
        const int m = m0 + ty * 8 + i;
#pragma unroll
        for (int j = 0; j < 8; ++j) {
            const int n = n0 + tx * 8 + j;
            if (n < N) {
                float v = acc[i][j];
                if (RES) v += R[(size_t)m * N + n];
                C[(size_t)m * N + n] = v;
            }
        }
    }
}

// ---------------- kernel 3: depthwise causal conv(4) + bias + SiLU ----------------
__global__ __launch_bounds__(256) void conv_silu_kernel(const float* __restrict__ zx,
                                                        const float* __restrict__ cw,
                                                        const float* __restrict__ cb,
                                                        float* __restrict__ outp) {
    const int idx = blockIdx.x * 256 + threadIdx.x;   // over NROWS*CONVDIM
    const int c  = idx % CONVDIM;
    const int bl = idx / CONVDIM;
    const int l  = bl & (SEQ - 1);
    const float* src = zx + (size_t)bl * DPROJ + DINNER + c;
    float s = cb[c];
#pragma unroll
    for (int k = 0; k < 4; ++k) {
        const int ls = l + k - 3;
        if (ls >= 0) s = fmaf(src[(ptrdiff_t)(k - 3) * DPROJ], cw[c * 4 + k], s);
    }
    outp[idx] = s / (1.f + __expf(-s));
}

// ---------------- kernel 4: sequential selective scan ----------------
// 1 WG per (b,h); thread t: p = t>>2 (head dim), nq = t&3 (16 n-states in regs).
// Stages SCH steps of x/B/C/dt/dA in LDS. Writes y in place over the conv x-slice.
#define SCH 32
__global__ __launch_bounds__(256) void scan_kernel(const float* __restrict__ zx,
                                                   float* __restrict__ conv,
                                                   const float* __restrict__ dt_bias,
                                                   const float* __restrict__ A_log,
                                                   const float* __restrict__ Dp) {
    const int b = blockIdx.x >> 3, h = blockIdx.x & 7;
    const int t = threadIdx.x;
    const int p = t >> 2, nq = t & 3;
    __shared__ float xs[SCH][64];
    __shared__ float Bsh[SCH][64];
    __shared__ float Csh[SCH][64];
    __shared__ float dts[SCH];
    __shared__ float dAs[SCH];

    float st[16];
#pragma unroll
    for (int j = 0; j < 16; ++j) st[j] = 0.f;

    const float aneg  = -__expf(A_log[h]);
    const float dpv   = Dp[h];
    const float dbias = dt_bias[h];
    const size_t browbase = (size_t)b * SEQ;

    for (int t0 = 0; t0 < SEQ; t0 += SCH) {
#pragma unroll
        for (int r = 0; r < 2; ++r) {
            const int idx = t + r * 256;           // 0..511 -> SCH*16 float4 per array
            const int s  = idx >> 4;
            const int c4 = (idx & 15) << 2;
            const size_t rowb = (browbase + t0 + s) * CONVDIM;
            *(float4*)&xs[s][c4]  = *(const float4*)(conv + rowb + h * 64 + c4);
            *(float4*)&Bsh[s][c4] = *(const float4*)(conv + rowb + DINNER + c4);
            *(float4*)&Csh[s][c4] = *(const float4*)(conv + rowb + DINNER + DSTATE + c4);
        }
        if (t < SCH) {
            const float draw = zx[(browbase + t0 + t) * DPROJ + (DPROJ - NHEADS) + h] + dbias;
            const float dtv  = (draw > 20.f) ? draw : log1pf(__expf(draw));
            dts[t] = dtv;
            dAs[t] = __expf(aneg * dtv);
        }
        __syncthreads();

        for (int s = 0; s < SCH; ++s) {
            const float dtv = dts[s];
            const float dav = dAs[s];
            const float xv  = xs[s][p];
            const float xh  = dtv * xv;
            const float4* Bp = (const float4*)&Bsh[s][nq * 16];
            const float4* Cp = (const float4*)&Csh[s][nq * 16];
            float yp = 0.f;
#pragma unroll
            for (int g = 0; g < 4; ++g) {
                const float4 bv = Bp[g];
                const float4 cv = Cp[g];
                st[g * 4 + 0] = fmaf(st[g * 4 + 0], dav, xh * bv.x); yp = fmaf(st[g * 4 + 0], cv.x, yp);
                st[g * 4 + 1] = fmaf(st[g * 4 + 1], dav, xh * bv.y); yp = fmaf(st[g * 4 + 1], cv.y, yp);
                st[g * 4 + 2] = fmaf(st[g * 4 + 2], dav, xh * bv.z); yp = fmaf(st[g * 4 + 2], cv.z, yp);
                st[g * 4 + 3] = fmaf(st[g * 4 + 3], dav, xh * bv.w); yp = fmaf(st[g * 4 + 3], cv.w, yp);
            }
            yp += __shfl_xor(yp, 1);
            yp += __shfl_xor(yp, 2);
            if (nq == 0)
                conv[(browbase + t0 + s) * CONVDIM + h * 64 + p] = yp + dpv * xv;
        }
        __syncthreads();
    }
}

// ---------------- kernel 5: y*silu(z) -> rmsnorm (D=512) -> yzn ----------------
__global__ __launch_bounds__(256) void gate_norm_kernel(const float* __restrict__ convp,
                                                        const float* __restrict__ zx,
                                                        const float* __restrict__ gw,
                                                        float* __restrict__ yzn) {
    const int row  = blockIdx.x * 4 + (threadIdx.x >> 6);
    const int lane = threadIdx.x & 63;
    const float* yrow = convp + (size_t)row * CONVDIM + lane * 8;
    const float* zrow = zx + (size_t)row * DPROJ + lane * 8;
    const float4 y0 = *(const float4*)(yrow);
    const float4 y1 = *(const float4*)(yrow + 4);
    const float4 z0 = *(const float4*)(zrow);
    const float4 z1 = *(const float4*)(zrow + 4);
    float v[8];
    v[0] = y0.x * z0.x / (1.f + __expf(-z0.x));
    v[1] = y0.y * z0.y / (1.f + __expf(-z0.y));
    v[2] = y0.z * z0.z / (1.f + __expf(-z0.z));
    v[3] = y0.w * z0.w / (1.f + __expf(-z0.w));
    v[4] = y1.x * z1.x / (1.f + __expf(-z1.x));
    v[5] = y1.y * z1.y / (1.f + __expf(-z1.y));
    v[6] = y1.z * z1.z / (1.f + __expf(-z1.z));
    v[7] = y1.w * z1.w / (1.f + __expf(-z1.w));
    float ss = 0.f;
#pragma unroll
    for (int i = 0; i < 8; ++i) ss += v[i] * v[i];
#pragma unroll
    for (int off = 1; off < 64; off <<= 1) ss += __shfl_xor(ss, off);
    const float rs = rsqrtf(ss * (1.0f / DINNER) + 1e-5f);
    const float* g = gw + lane * 8;
    float4 o0, o1;
    o0.x = v[0] * rs * g[0]; o0.y = v[1] * rs * g[1];
    o0.z = v[2] * rs * g[2]; o0.w = v[3] * rs * g[3];
    o1.x = v[4] * rs * g[4]; o1.y = v[5] * rs * g[5];
    o1.z = v[6] * rs * g[6]; o1.w = v[7] * rs * g[7];
    float* orow = yzn + (size_t)row * DINNER + lane * 8;
    *(float4*)(orow)     = o0;
    *(float4*)(orow + 4) = o1;
}

// ---------------- launch ----------------
extern "C" void kernel_launch(void* const* d_in, const int* in_sizes, int n_in,
                              void* d_out, int out_size, void* d_ws, size_t ws_size,
                              hipStream_t stream) {
    (void)in_sizes; (void)n_in; (void)out_size; (void)d_ws; (void)ws_size;
    const float* x      = (const float*)d_in[0];
    const float* W_in   = (const float*)d_in[1];
    const float* conv_w = (const float*)d_in[2];
    const float* conv_b = (const float*)d_in[3];
    const float* dt_b   = (const float*)d_in[4];
    const float* A_log  = (const float*)d_in[5];
    const float* Dp     = (const float*)d_in[6];
    const float* g_w    = (const float*)d_in[7];
    const float* n_w    = (const float*)d_in[8];
    const float* W_out  = (const float*)d_in[9];
    float* out = (float*)d_out;

    float *xn, *zx, *cv, *yzn;
    hipGetSymbolAddress((void**)&xn,  HIP_SYMBOL(g_xn));
    hipGetSymbolAddress((void**)&zx,  HIP_SYMBOL(g_zx));
    hipGetSymbolAddress((void**)&cv,  HIP_SYMBOL(g_conv));
    hipGetSymbolAddress((void**)&yzn, HIP_SYMBOL(g_yzn));

    rmsnorm_x_kernel<<<NROWS / 4, 256, 0, stream>>>(x, n_w, xn);

    gemm_nt<false><<<dim3((DPROJ + 127) / 128, NROWS / 128), 256, 0, stream>>>(
        xn, W_in, nullptr, zx, NROWS, DPROJ, DMODEL);

    conv_silu_kernel<<<(NROWS * CONVDIM) / 256, 256, 0, stream>>>(zx, conv_w, conv_b, cv);

    scan_kernel<<<BATCH * NHEADS, 256, 0, stream>>>(zx, cv, dt_b, A_log, Dp);

    gate_norm_kernel<<<NROWS / 4, 256, 0, stream>>>(cv, zx, g_w, yzn);

    gemm_nt<true><<<dim3(DMODEL / 128, NROWS / 128), 256, 0, stream>>>(
        yzn, W_out, x, out, NROWS, DMODEL, DINNER);
}

// Round 2
// 803.606 us; speedup vs baseline: 2.1997x; 2.1997x over previous
//
#include <hip/hip_runtime.h>
#include <math.h>

#define BATCH   8
#define SEQ     4096
#define DMODEL  256
#define DINNER  512
#define DSTATE  64
#define NHEADS  8
#define HEADDIM 64
#define CONVDIM 640          // DINNER + 2*DSTATE
#define DPROJ   1160         // 2*DINNER + 2*DSTATE + NHEADS
#define NROWS   (BATCH*SEQ)  // 32768
#define CHUNK   64
#define NCHUNK  (SEQ/CHUNK)  // 64

// ---- static workspace (BSS, allocated at module load; ws_size-independent) ----
__device__ float g_xn[(size_t)NROWS * DMODEL];    //  33.5 MB
__device__ float g_zx[(size_t)NROWS * DPROJ];     // 152.0 MB
__device__ float g_conv[(size_t)NROWS * CONVDIM]; //  83.9 MB (x part overwritten by y in scan)
__device__ float g_yzn[(size_t)NROWS * DINNER];   //  67.1 MB
__device__ float g_lstate[(size_t)BATCH * NHEADS * NCHUNK * HEADDIM * DSTATE]; // 67.1 MB
__device__ float g_decayC[BATCH * NHEADS * NCHUNK];

// ---------------- kernel 1: rmsnorm of x (D=256), one wave per row ----------------
__global__ __launch_bounds__(256) void rmsnorm_x_kernel(const float* __restrict__ x,
                                                        const float* __restrict__ w,
                                                        float* __restrict__ xn) {
    const int row  = blockIdx.x * 4 + (threadIdx.x >> 6);
    const int lane = threadIdx.x & 63;
    const float4 v = *(const float4*)(x + (size_t)row * DMODEL + lane * 4);
    float ss = v.x * v.x + v.y * v.y + v.z * v.z + v.w * v.w;
#pragma unroll
    for (int off = 1; off < 64; off <<= 1) ss += __shfl_xor(ss, off);
    const float rs = rsqrtf(ss * (1.0f / DMODEL) + 1.1920929e-7f);
    const float4 wv = *(const float4*)(w + lane * 4);
    float4 o;
    o.x = v.x * rs * wv.x; o.y = v.y * rs * wv.y;
    o.z = v.z * rs * wv.z; o.w = v.w * rs * wv.w;
    *(float4*)(xn + (size_t)row * DMODEL + lane * 4) = o;
}

// ---------------- fp32 SIMT GEMM: C[M][N] = A[M][K] * B[N][K]^T (+ optional residual) ----
template <bool RES>
__global__ __launch_bounds__(256) void gemm_nt(const float* __restrict__ A,
                                               const float* __restrict__ B,
                                               const float* __restrict__ R,
                                               float* __restrict__ C,
                                               int M, int N, int K) {
    __shared__ float As[16][132];
    __shared__ float Bs[16][132];
    const int tid = threadIdx.x;
    const int tx = tid & 15, ty = tid >> 4;
    const int m0 = blockIdx.y * 128, n0 = blockIdx.x * 128;

    float acc[8][8];
#pragma unroll
    for (int i = 0; i < 8; ++i)
#pragma unroll
        for (int j = 0; j < 8; ++j) acc[i][j] = 0.f;

    for (int k0 = 0; k0 < K; k0 += 16) {
#pragma unroll
        for (int r = 0; r < 2; ++r) {
            const int idx = tid + r * 256;       // 0..511
            const int mm  = idx >> 2;            // 0..127
            const int k4  = (idx & 3) << 2;      // 0,4,8,12
            const float4 va = *(const float4*)(A + (size_t)(m0 + mm) * K + (k0 + k4));
            As[k4 + 0][mm] = va.x; As[k4 + 1][mm] = va.y;
            As[k4 + 2][mm] = va.z; As[k4 + 3][mm] = va.w;
            float4 vb = make_float4(0.f, 0.f, 0.f, 0.f);
            if (n0 + mm < N) vb = *(const float4*)(B + (size_t)(n0 + mm) * K + (k0 + k4));
            Bs[k4 + 0][mm] = vb.x; Bs[k4 + 1][mm] = vb.y;
            Bs[k4 + 2][mm] = vb.z; Bs[k4 + 3][mm] = vb.w;
        }
        __syncthreads();
#pragma unroll
        for (int kk = 0; kk < 16; ++kk) {
            float a[8], b[8];
            *(float4*)&a[0] = *(const float4*)&As[kk][ty * 8];
            *(float4*)&a[4] = *(const float4*)&As[kk][ty * 8 + 4];
            *(float4*)&b[0] = *(const float4*)&Bs[kk][tx * 8];
            *(float4*)&b[4] = *(const float4*)&Bs[kk][tx * 8 + 4];
#pragma unroll
            for (int i = 0; i < 8; ++i)
#pragma unroll
                for (int j = 0; j < 8; ++j) acc[i][j] = fmaf(a[i], b[j], acc[i][j]);
        }
        __syncthreads();
    }
#pragma unroll
    for (int i = 0; i < 8; ++i) {
        const int m = m0 + ty * 8 + i;
#pragma unroll
        for (int j = 0; j < 8; ++j) {
            const int n = n0 + tx * 8 + j;
            if (n < N) {
                float v = acc[i][j];
                if (RES) v += R[(size_t)m * N + n];
                C[(size_t)m * N + n] = v;
            }
        }
    }
}

// ---------------- kernel 3: depthwise causal conv(4) + bias + SiLU ----------------
__global__ __launch_bounds__(256) void conv_silu_kernel(const float* __restrict__ zx,
                                                        const float* __restrict__ cw,
                                                        const float* __restrict__ cb,
                                                        float* __restrict__ outp) {
    const int idx = blockIdx.x * 256 + threadIdx.x;   // over NROWS*CONVDIM
    const int c  = idx % CONVDIM;
    const int bl = idx / CONVDIM;
    const int l  = bl & (SEQ - 1);
    const float* src = zx + (size_t)bl * DPROJ + DINNER + c;
    float s = cb[c];
#pragma unroll
    for (int k = 0; k < 4; ++k) {
        const int ls = l + k - 3;
        if (ls >= 0) s = fmaf(src[(ptrdiff_t)(k - 3) * DPROJ], cw[c * 4 + k], s);
    }
    outp[idx] = s / (1.f + __expf(-s));
}

// ---------------- scan pass 1: per-chunk local final state + chunk decay ----------------
// WG = (b,h,chunk); 256 threads = (p = t>>2, nq = t&3); 16 states/thread in regs.
__global__ __launch_bounds__(256) void chunk_state_kernel(const float* __restrict__ zx,
                                                          const float* __restrict__ conv,
                                                          const float* __restrict__ dt_bias,
                                                          const float* __restrict__ A_log,
                                                          float* __restrict__ lstate,
                                                          float* __restrict__ decayC) {
    const int bhc = blockIdx.x;
    const int c   = bhc & (NCHUNK - 1);
    const int bh  = bhc >> 6;
    const int h   = bh & (NHEADS - 1);
    const int b   = bh >> 3;
    const int t   = threadIdx.x;
    const int p = t >> 2, nq = t & 3;
    __shared__ float xs[CHUNK][64];
    __shared__ float Bsh[CHUNK][64];
    __shared__ float dts[CHUNK];
    __shared__ float dAs[CHUNK];

    const size_t row0 = (size_t)b * SEQ + (size_t)c * CHUNK;
#pragma unroll
    for (int r = 0; r < 4; ++r) {
        const int idx = t + r * 256;             // 0..1023
        const int s  = idx >> 4;
        const int c4 = (idx & 15) << 2;
        const size_t rowb = (row0 + s) * CONVDIM;
        *(float4*)&xs[s][c4]  = *(const float4*)(conv + rowb + h * 64 + c4);
        *(float4*)&Bsh[s][c4] = *(const float4*)(conv + rowb + DINNER + c4);
    }
    const float aneg  = -__expf(A_log[h]);
    const float dbias = dt_bias[h];
    if (t < CHUNK) {
        const float draw = zx[(row0 + t) * DPROJ + (DPROJ - NHEADS) + h] + dbias;
        const float dtv  = (draw > 20.f) ? draw : log1pf(__expf(draw));
        dts[t] = dtv;
        dAs[t] = __expf(aneg * dtv);
        float v = dtv;
#pragma unroll
        for (int off = 1; off < 64; off <<= 1) v += __shfl_xor(v, off);
        if (t == 0) decayC[bhc] = __expf(aneg * v);
    }
    __syncthreads();

    float st[16];
#pragma unroll
    for (int j = 0; j < 16; ++j) st[j] = 0.f;

    for (int s = 0; s < CHUNK; ++s) {
        const float dav = dAs[s];
        const float xh  = dts[s] * xs[s][p];
        const float4* Bp = (const float4*)&Bsh[s][nq * 16];
#pragma unroll
        for (int g = 0; g < 4; ++g) {
            const float4 bv = Bp[g];
            st[g * 4 + 0] = fmaf(st[g * 4 + 0], dav, xh * bv.x);
            st[g * 4 + 1] = fmaf(st[g * 4 + 1], dav, xh * bv.y);
            st[g * 4 + 2] = fmaf(st[g * 4 + 2], dav, xh * bv.z);
            st[g * 4 + 3] = fmaf(st[g * 4 + 3], dav, xh * bv.w);
        }
    }
    float* lp = lstate + ((size_t)bhc * HEADDIM + p) * DSTATE + nq * 16;
#pragma unroll
    for (int g = 0; g < 4; ++g)
        *(float4*)(lp + g * 4) = make_float4(st[g * 4], st[g * 4 + 1], st[g * 4 + 2], st[g * 4 + 3]);
}

// ---------------- scan pass 2: inter-chunk recurrence; lstate -> exclusive prefix (in place) --
__global__ __launch_bounds__(256) void state_prefix_kernel(float* __restrict__ lstate,
                                                           const float* __restrict__ decayC) {
    const int idx = blockIdx.x * 256 + threadIdx.x;   // over BATCH*NHEADS*4096
    const int bh = idx >> 12;
    const int pn = idx & 4095;
    float S = 0.f;
    for (int c = 0; c < NCHUNK; ++c) {
        float* ptr = lstate + (((size_t)bh * NCHUNK + c) << 12) + pn;
        const float l = *ptr;
        *ptr = S;
        S = fmaf(S, decayC[bh * NCHUNK + c], l);
    }
}

// ---------------- scan pass 3: per-chunk scan from prefix state, emit y ----------------
__global__ __launch_bounds__(256) void chunk_scan_kernel(const float* __restrict__ zx,
                                                         float* __restrict__ conv,
                                                         const float* __restrict__ dt_bias,
                                                         const float* __restrict__ A_log,
                                                         const float* __restrict__ Dp,
                                                         const float* __restrict__ lstate) {
    const int bhc = blockIdx.x;
    const int c   = bhc & (NCHUNK - 1);
    const int bh  = bhc >> 6;
    const int h   = bh & (NHEADS - 1);
    const int b   = bh >> 3;
    const int t   = threadIdx.x;
    const int p = t >> 2, nq = t & 3;
    __shared__ float xs[CHUNK][64];
    __shared__ float Bsh[CHUNK][64];
    __shared__ float Csh[CHUNK][64];
    __shared__ float dts[CHUNK];
    __shared__ float dAs[CHUNK];

    const size_t row0 = (size_t)b * SEQ + (size_t)c * CHUNK;
#pragma unroll
    for (int r = 0; r < 4; ++r) {
        const int idx = t + r * 256;
        const int s  = idx >> 4;
        const int c4 = (idx & 15) << 2;
        const size_t rowb = (row0 + s) * CONVDIM;
        *(float4*)&xs[s][c4]  = *(const float4*)(conv + rowb + h * 64 + c4);
        *(float4*)&Bsh[s][c4] = *(const float4*)(conv + rowb + DINNER + c4);
        *(float4*)&Csh[s][c4] = *(const float4*)(conv + rowb + DINNER + DSTATE + c4);
    }
    const float aneg  = -__expf(A_log[h]);
    const float dbias = dt_bias[h];
    const float dpv   = Dp[h];
    if (t < CHUNK) {
        const float draw = zx[(row0 + t) * DPROJ + (DPROJ - NHEADS) + h] + dbias;
        const float dtv  = (draw > 20.f) ? draw : log1pf(__expf(draw));
        dts[t] = dtv;
        dAs[t] = __expf(aneg * dtv);
    }
    __syncthreads();

    float st[16];
    {
        const float* lp = lstate + ((size_t)bhc * HEADDIM + p) * DSTATE + nq * 16;
#pragma unroll
        for (int g = 0; g < 4; ++g) {
            const float4 v = *(const float4*)(lp + g * 4);
            st[g * 4] = v.x; st[g * 4 + 1] = v.y; st[g * 4 + 2] = v.z; st[g * 4 + 3] = v.w;
        }
    }

    for (int s = 0; s < CHUNK; ++s) {
        const float dav = dAs[s];
        const float xv  = xs[s][p];
        const float xh  = dts[s] * xv;
        const float4* Bp = (const float4*)&Bsh[s][nq * 16];
        const float4* Cp = (const float4*)&Csh[s][nq * 16];
        float yp = 0.f;
#pragma unroll
        for (int g = 0; g < 4; ++g) {
            const float4 bv = Bp[g];
            const float4 cv = Cp[g];
            st[g * 4 + 0] = fmaf(st[g * 4 + 0], dav, xh * bv.x); yp = fmaf(st[g * 4 + 0], cv.x, yp);
            st[g * 4 + 1] = fmaf(st[g * 4 + 1], dav, xh * bv.y); yp = fmaf(st[g * 4 + 1], cv.y, yp);
            st[g * 4 + 2] = fmaf(st[g * 4 + 2], dav, xh * bv.z); yp = fmaf(st[g * 4 + 2], cv.z, yp);
            st[g * 4 + 3] = fmaf(st[g * 4 + 3], dav, xh * bv.w); yp = fmaf(st[g * 4 + 3], cv.w, yp);
        }
        yp += __shfl_xor(yp, 1);
        yp += __shfl_xor(yp, 2);
        if (nq == 0)
            conv[(row0 + s) * CONVDIM + h * 64 + p] = yp + dpv * xv;
    }
}

// ---------------- kernel 5: y*silu(z) -> rmsnorm (D=512) -> yzn ----------------
__global__ __launch_bounds__(256) void gate_norm_kernel(const float* __restrict__ convp,
                                                        const float* __restrict__ zx,
                                                        const float* __restrict__ gw,
                                                        float* __restrict__ yzn) {
    const int row  = blockIdx.x * 4 + (threadIdx.x >> 6);
    const int lane = threadIdx.x & 63;
    const float* yrow = convp + (size_t)row * CONVDIM + lane * 8;
    const float* zrow = zx + (size_t)row * DPROJ + lane * 8;
    const float4 y0 = *(const float4*)(yrow);
    const float4 y1 = *(const float4*)(yrow + 4);
    const float4 z0 = *(const float4*)(zrow);
    const float4 z1 = *(const float4*)(zrow + 4);
    float v[8];
    v[0] = y0.x * z0.x / (1.f + __expf(-z0.x));
    v[1] = y0.y * z0.y / (1.f + __expf(-z0.y));
    v[2] = y0.z * z0.z / (1.f + __expf(-z0.z));
    v[3] = y0.w * z0.w / (1.f + __expf(-z0.w));
    v[4] = y1.x * z1.x / (1.f + __expf(-z1.x));
    v[5] = y1.y * z1.y / (1.f + __expf(-z1.y));
    v[6] = y1.z * z1.z / (1.f + __expf(-z1.z));
    v[7] = y1.w * z1.w / (1.f + __expf(-z1.w));
    float ss = 0.f;
#pragma unroll
    for (int i = 0; i < 8; ++i) ss += v[i] * v[i];
#pragma unroll
    for (int off = 1; off < 64; off <<= 1) ss += __shfl_xor(ss, off);
    const float rs = rsqrtf(ss * (1.0f / DINNER) + 1e-5f);
    const float* g = gw + lane * 8;
    float4 o0, o1;
    o0.x = v[0] * rs * g[0]; o0.y = v[1] * rs * g[1];
    o0.z = v[2] * rs * g[2]; o0.w = v[3] * rs * g[3];
    o1.x = v[4] * rs * g[4]; o1.y = v[5] * rs * g[5];
    o1.z = v[6] * rs * g[6]; o1.w = v[7] * rs * g[7];
    float* orow = yzn + (size_t)row * DINNER + lane * 8;
    *(float4*)(orow)     = o0;
    *(float4*)(orow + 4) = o1;
}

// ---------------- launch ----------------
extern "C" void kernel_launch(void* const* d_in, const int* in_sizes, int n_in,
                              void* d_out, int out_size, void* d_ws, size_t ws_size,
                              hipStream_t stream) {
    (void)in_sizes; (void)n_in; (void)out_size; (void)d_ws; (void)ws_size;
    const float* x      = (const float*)d_in[0];
    const float* W_in   = (const float*)d_in[1];
    const float* conv_w = (const float*)d_in[2];
    const float* conv_b = (const float*)d_in[3];
    const float* dt_b   = (const float*)d_in[4];
    const float* A_log  = (const float*)d_in[5];
    const float* Dp     = (const float*)d_in[6];
    const float* g_w    = (const float*)d_in[7];
    const float* n_w    = (const float*)d_in[8];
    const float* W_out  = (const float*)d_in[9];
    float* out = (float*)d_out;

    float *xn, *zx, *cv, *yzn, *lst, *dcy;
    hipGetSymbolAddress((void**)&xn,  HIP_SYMBOL(g_xn));
    hipGetSymbolAddress((void**)&zx,  HIP_SYMBOL(g_zx));
    hipGetSymbolAddress((void**)&cv,  HIP_SYMBOL(g_conv));
    hipGetSymbolAddress((void**)&yzn, HIP_SYMBOL(g_yzn));
    hipGetSymbolAddress((void**)&lst, HIP_SYMBOL(g_lstate));
    hipGetSymbolAddress((void**)&dcy, HIP_SYMBOL(g_decayC));

    rmsnorm_x_kernel<<<NROWS / 4, 256, 0, stream>>>(x, n_w, xn);

    gemm_nt<false><<<dim3((DPROJ + 127) / 128, NROWS / 128), 256, 0, stream>>>(
        xn, W_in, nullptr, zx, NROWS, DPROJ, DMODEL);

    conv_silu_kernel<<<(NROWS * CONVDIM) / 256, 256, 0, stream>>>(zx, conv_w, conv_b, cv);

    chunk_state_kernel<<<BATCH * NHEADS * NCHUNK, 256, 0, stream>>>(zx, cv, dt_b, A_log, lst, dcy);
    state_prefix_kernel<<<(BATCH * NHEADS * HEADDIM * DSTATE) / 256, 256, 0, stream>>>(lst, dcy);
    chunk_scan_kernel<<<BATCH * NHEADS * NCHUNK, 256, 0, stream>>>(zx, cv, dt_b, A_log, Dp, lst);

    gate_norm_kernel<<<NROWS / 4, 256, 0, stream>>>(cv, zx, g_w, yzn);

    gemm_nt<true><<<dim3(DMODEL / 128, NROWS / 128), 256, 0, stream>>>(
        yzn, W_out, x, out, NROWS, DMODEL, DINNER);
}

// Round 3
// 484.548 us; speedup vs baseline: 3.6481x; 1.6585x over previous
//
#include <hip/hip_runtime.h>
#include <math.h>

#define BATCH   8
#define SEQ     4096
#define DMODEL  256
#define DINNER  512
#define DSTATE  64
#define NHEADS  8
#define HEADDIM 64
#define CONVDIM 640          // DINNER + 2*DSTATE
#define DPROJ   1160         // 2*DINNER + 2*DSTATE + NHEADS
#define NROWS   (BATCH*SEQ)  // 32768
#define CHUNK   64
#define NCHUNK  (SEQ/CHUNK)  // 64
#define NPAD    1280         // DPROJ padded to mult of 128 for bf16 W_in

typedef short bf16x8 __attribute__((ext_vector_type(8)));
typedef short short8v __attribute__((ext_vector_type(8)));
typedef float f32x4 __attribute__((ext_vector_type(4)));

// ---- static workspace (BSS, allocated at module load; ws_size-independent) ----
__device__ short g_xn[(size_t)NROWS * DMODEL];     // bf16 16.8 MB
__device__ float g_zx[(size_t)NROWS * DPROJ];      // 152.0 MB
__device__ float g_conv[(size_t)NROWS * CONVDIM];  //  83.9 MB (x part overwritten by y)
__device__ short g_yzn[(size_t)NROWS * DINNER];    // bf16 33.5 MB
__device__ float g_lstate[(size_t)BATCH * NHEADS * NCHUNK * HEADDIM * DSTATE]; // 67.1 MB
__device__ float g_decayC[BATCH * NHEADS * NCHUNK];
__device__ short g_Winb[(size_t)NPAD * DMODEL];    // bf16 W_in, zero-padded rows
__device__ short g_Woutb[(size_t)DMODEL * DINNER]; // bf16 W_out

__device__ __forceinline__ short f2bf(float f) {   // RNE fp32 -> bf16
    unsigned u = __float_as_uint(f);
    u += 0x7fff + ((u >> 16) & 1);
    return (short)(u >> 16);
}

__device__ __forceinline__ void stage16(const void* gsrc, void* ldst) {
    __builtin_amdgcn_global_load_lds(
        (const __attribute__((address_space(1))) void*)gsrc,
        (__attribute__((address_space(3))) void*)ldst, 16, 0, 0);
}

// ---------------- weight convert: fp32 -> bf16 with flat zero-pad tail ----------------
__global__ __launch_bounds__(256) void convert_bf16_kernel(const float* __restrict__ src,
                                                           short* __restrict__ dst,
                                                           int n_valid, int n_total) {
    const int i = blockIdx.x * 256 + threadIdx.x;
    if (i < n_total) dst[i] = (i < n_valid) ? f2bf(src[i]) : (short)0;
}

// ---------------- kernel 1: rmsnorm of x (D=256) -> bf16, one wave per row ----------------
__global__ __launch_bounds__(256) void rmsnorm_x_kernel(const float* __restrict__ x,
                                                        const float* __restrict__ w,
                                                        short* __restrict__ xn) {
    const int row  = blockIdx.x * 4 + (threadIdx.x >> 6);
    const int lane = threadIdx.x & 63;
    const float4 v = *(const float4*)(x + (size_t)row * DMODEL + lane * 4);
    float ss = v.x * v.x + v.y * v.y + v.z * v.z + v.w * v.w;
#pragma unroll
    for (int off = 1; off < 64; off <<= 1) ss += __shfl_xor(ss, off);
    const float rs = rsqrtf(ss * (1.0f / DMODEL) + 1.1920929e-7f);
    const float4 wv = *(const float4*)(w + lane * 4);
    short4 o;
    o.x = f2bf(v.x * rs * wv.x); o.y = f2bf(v.y * rs * wv.y);
    o.z = f2bf(v.z * rs * wv.z); o.w = f2bf(v.w * rs * wv.w);
    *(short4*)(xn + (size_t)row * DMODEL + lane * 4) = o;
}

// ---------------- bf16 MFMA GEMM (m97 structure): C[M][N] = A[M][K] * B[N][K]^T ----------
// 128x128 tile, BK=32, 256 threads = 4 waves, each wave 64x64 (4x4 frags of 16x16x32).
// B must be padded to gridDim.x*128 rows; store guarded by n<N.
template <bool RES>
__global__ __launch_bounds__(256) void gemm_bf16_nt(const short* __restrict__ A,
                                                    const short* __restrict__ B,
                                                    const float* __restrict__ R,
                                                    float* __restrict__ C,
                                                    int M, int N, int K) {
    __shared__ __align__(16) short Asl[128 * 32];
    __shared__ __align__(16) short Bsl[128 * 32];
    const int tid  = threadIdx.x;
    const int lane = tid & 63;
    const int wid  = tid >> 6;
    const int m0 = blockIdx.y * 128, n0 = blockIdx.x * 128;
    const int wrow = (wid >> 1) * 64, wcol = (wid & 1) * 64;

    f32x4 acc[4][4];
#pragma unroll
    for (int m = 0; m < 4; ++m)
#pragma unroll
        for (int n = 0; n < 4; ++n) acc[m][n] = (f32x4)0.f;

    const int wbase = (tid & 0xC0) * 8;       // wave-uniform LDS element base (lane*8 added by HW)

    for (int k0 = 0; k0 < K; k0 += 32) {
#pragma unroll
        for (int r = 0; r < 2; ++r) {
            const int idx = r * 256 + tid;
            const int row = idx >> 2;
            const int ko  = (idx & 3) * 8;
            stage16(A + (size_t)(m0 + row) * K + k0 + ko, Asl + r * 2048 + wbase);
            stage16(B + (size_t)(n0 + row) * K + k0 + ko, Bsl + r * 2048 + wbase);
        }
        __syncthreads();
        bf16x8 af[4], bfr[4];
#pragma unroll
        for (int m = 0; m < 4; ++m)
            af[m] = *(const bf16x8*)(Asl + (wrow + m * 16 + (lane & 15)) * 32 + (lane >> 4) * 8);
#pragma unroll
        for (int n = 0; n < 4; ++n)
            bfr[n] = *(const bf16x8*)(Bsl + (wcol + n * 16 + (lane & 15)) * 32 + (lane >> 4) * 8);
#pragma unroll
        for (int m = 0; m < 4; ++m)
#pragma unroll
            for (int n = 0; n < 4; ++n)
                acc[m][n] = __builtin_amdgcn_mfma_f32_16x16x32_bf16(af[m], bfr[n], acc[m][n], 0, 0, 0);
        __syncthreads();
    }

    const int r0 = (lane >> 4) * 4;
#pragma unroll
    for (int m = 0; m < 4; ++m) {
        const int grow = m0 + wrow + m * 16 + r0;
#pragma unroll
        for (int n = 0; n < 4; ++n) {
            const int gcol = n0 + wcol + n * 16 + (lane & 15);
            if (gcol < N) {
#pragma unroll
                for (int reg = 0; reg < 4; ++reg) {
                    float v = acc[m][n][reg];
                    if (RES) v += R[(size_t)(grow + reg) * N + gcol];
                    C[(size_t)(grow + reg) * N + gcol] = v;
                }
            }
        }
    }
}

// ---------------- dt fixup: recompute the 8 dt columns of zx in fp32 ----------------
// One wave per row: rmsnorm in-register, then 8 dot-256 against W_in rows 1152..1159.
__global__ __launch_bounds__(256) void dt_fix_kernel(const float* __restrict__ x,
                                                     const float* __restrict__ nw,
                                                     const float* __restrict__ W_in,
                                                     float* __restrict__ zx) {
    const int row  = blockIdx.x * 4 + (threadIdx.x >> 6);
    const int lane = threadIdx.x & 63;
    const float4 v = *(const float4*)(x + (size_t)row * DMODEL + lane * 4);
    float ss = v.x * v.x + v.y * v.y + v.z * v.z + v.w * v.w;
#pragma unroll
    for (int off = 1; off < 64; off <<= 1) ss += __shfl_xor(ss, off);
    const float rs = rsqrtf(ss * (1.0f / DMODEL) + 1.1920929e-7f);
    const float4 wv = *(const float4*)(nw + lane * 4);
    const float4 xn4 = make_float4(v.x * rs * wv.x, v.y * rs * wv.y,
                                   v.z * rs * wv.z, v.w * rs * wv.w);
#pragma unroll
    for (int h = 0; h < NHEADS; ++h) {
        const float4 ww = *(const float4*)(W_in + (size_t)(DPROJ - NHEADS + h) * DMODEL + lane * 4);
        float p = xn4.x * ww.x + xn4.y * ww.y + xn4.z * ww.z + xn4.w * ww.w;
#pragma unroll
        for (int off = 1; off < 64; off <<= 1) p += __shfl_xor(p, off);
        if (lane == 0) zx[(size_t)row * DPROJ + (DPROJ - NHEADS) + h] = p;
    }
}

// ---------------- depthwise causal conv(4) + bias + SiLU ----------------
__global__ __launch_bounds__(256) void conv_silu_kernel(const float* __restrict__ zx,
                                                        const float* __restrict__ cw,
                                                        const float* __restrict__ cb,
                                                        float* __restrict__ outp) {
    const int idx = blockIdx.x * 256 + threadIdx.x;   // over NROWS*CONVDIM
    const int c  = idx % CONVDIM;
    const int bl = idx / CONVDIM;
    const int l  = bl & (SEQ - 1);
    const float* src = zx + (size_t)bl * DPROJ + DINNER + c;
    float s = cb[c];
#pragma unroll
    for (int k = 0; k < 4; ++k) {
        const int ls = l + k - 3;
        if (ls >= 0) s = fmaf(src[(ptrdiff_t)(k - 3) * DPROJ], cw[c * 4 + k], s);
    }
    outp[idx] = s / (1.f + __expf(-s));
}

// ---------------- scan pass 1: per-chunk local final state + chunk decay ----------------
__global__ __launch_bounds__(256) void chunk_state_kernel(const float* __restrict__ zx,
                                                          const float* __restrict__ conv,
                                                          const float* __restrict__ dt_bias,
                                                          const float* __restrict__ A_log,
                                                          float* __restrict__ lstate,
                                                          float* __restrict__ decayC) {
    const int bhc = blockIdx.x;
    const int c   = bhc & (NCHUNK - 1);
    const int bh  = bhc >> 6;
    const int h   = bh & (NHEADS - 1);
    const int b   = bh >> 3;
    const int t   = threadIdx.x;
    const int p = t >> 2, nq = t & 3;
    __shared__ float xs[CHUNK][64];
    __shared__ float Bsh[CHUNK][64];
    __shared__ float dts[CHUNK];
    __shared__ float dAs[CHUNK];

    const size_t row0 = (size_t)b * SEQ + (size_t)c * CHUNK;
#pragma unroll
    for (int r = 0; r < 4; ++r) {
        const int idx = t + r * 256;             // 0..1023
        const int s  = idx >> 4;
        const int c4 = (idx & 15) << 2;
        const size_t rowb = (row0 + s) * CONVDIM;
        *(float4*)&xs[s][c4]  = *(const float4*)(conv + rowb + h * 64 + c4);
        *(float4*)&Bsh[s][c4] = *(const float4*)(conv + rowb + DINNER + c4);
    }
    const float aneg  = -__expf(A_log[h]);
    const float dbias = dt_bias[h];
    if (t < CHUNK) {
        const float draw = zx[(row0 + t) * DPROJ + (DPROJ - NHEADS) + h] + dbias;
        const float dtv  = (draw > 20.f) ? draw : log1pf(__expf(draw));
        dts[t] = dtv;
        dAs[t] = __expf(aneg * dtv);
        float v = dtv;
#pragma unroll
        for (int off = 1; off < 64; off <<= 1) v += __shfl_xor(v, off);
        if (t == 0) decayC[bhc] = __expf(aneg * v);
    }
    __syncthreads();

    float st[16];
#pragma unroll
    for (int j = 0; j < 16; ++j) st[j] = 0.f;

    for (int s = 0; s < CHUNK; ++s) {
        const float dav = dAs[s];
        const float xh  = dts[s] * xs[s][p];
        const float4* Bp = (const float4*)&Bsh[s][nq * 16];
#pragma unroll
        for (int g = 0; g < 4; ++g) {
            const float4 bv = Bp[g];
            st[g * 4 + 0] = fmaf(st[g * 4 + 0], dav, xh * bv.x);
            st[g * 4 + 1] = fmaf(st[g * 4 + 1], dav, xh * bv.y);
            st[g * 4 + 2] = fmaf(st[g * 4 + 2], dav, xh * bv.z);
            st[g * 4 + 3] = fmaf(st[g * 4 + 3], dav, xh * bv.w);
        }
    }
    float* lp = lstate + ((size_t)bhc * HEADDIM + p) * DSTATE + nq * 16;
#pragma unroll
    for (int g = 0; g < 4; ++g)
        *(float4*)(lp + g * 4) = make_float4(st[g * 4], st[g * 4 + 1], st[g * 4 + 2], st[g * 4 + 3]);
}

// ---------------- scan pass 2: inter-chunk recurrence; lstate -> exclusive prefix ----------
__global__ __launch_bounds__(256) void state_prefix_kernel(float* __restrict__ lstate,
                                                           const float* __restrict__ decayC) {
    const int idx = blockIdx.x * 256 + threadIdx.x;   // over BATCH*NHEADS*4096
    const int bh = idx >> 12;
    const int pn = idx & 4095;
    float S = 0.f;
    for (int c = 0; c < NCHUNK; ++c) {
        float* ptr = lstate + (((size_t)bh * NCHUNK + c) << 12) + pn;
        const float l = *ptr;
        *ptr = S;
        S = fmaf(S, decayC[bh * NCHUNK + c], l);
    }
}

// ---------------- scan pass 3: per-chunk scan from prefix state, emit y ----------------
__global__ __launch_bounds__(256) void chunk_scan_kernel(const float* __restrict__ zx,
                                                         float* __restrict__ conv,
                                                         const float* __restrict__ dt_bias,
                                                         const float* __restrict__ A_log,
                                                         const float* __restrict__ Dp,
                                                         const float* __restrict__ lstate) {
    const int bhc = blockIdx.x;
    const int c   = bhc & (NCHUNK - 1);
    const int bh  = bhc >> 6;
    const int h   = bh & (NHEADS - 1);
    const int b   = bh >> 3;
    const int t   = threadIdx.x;
    const int p = t >> 2, nq = t & 3;
    __shared__ float xs[CHUNK][64];
    __shared__ float Bsh[CHUNK][64];
    __shared__ float Csh[CHUNK][64];
    __shared__ float dts[CHUNK];
    __shared__ float dAs[CHUNK];

    const size_t row0 = (size_t)b * SEQ + (size_t)c * CHUNK;
#pragma unroll
    for (int r = 0; r < 4; ++r) {
        const int idx = t + r * 256;
        const int s  = idx >> 4;
        const int c4 = (idx & 15) << 2;
        const size_t rowb = (row0 + s) * CONVDIM;
        *(float4*)&xs[s][c4]  = *(const float4*)(conv + rowb + h * 64 + c4);
        *(float4*)&Bsh[s][c4] = *(const float4*)(conv + rowb + DINNER + c4);
        *(float4*)&Csh[s][c4] = *(const float4*)(conv + rowb + DINNER + DSTATE + c4);
    }
    const float aneg  = -__expf(A_log[h]);
    const float dbias = dt_bias[h];
    const float dpv   = Dp[h];
    if (t < CHUNK) {
        const float draw = zx[(row0 + t) * DPROJ + (DPROJ - NHEADS) + h] + dbias;
        const float dtv  = (draw > 20.f) ? draw : log1pf(__expf(draw));
        dts[t] = dtv;
        dAs[t] = __expf(aneg * dtv);
    }
    __syncthreads();

    float st[16];
    {
        const float* lp = lstate + ((size_t)bhc * HEADDIM + p) * DSTATE + nq * 16;
#pragma unroll
        for (int g = 0; g < 4; ++g) {
            const float4 v = *(const float4*)(lp + g * 4);
            st[g * 4] = v.x; st[g * 4 + 1] = v.y; st[g * 4 + 2] = v.z; st[g * 4 + 3] = v.w;
        }
    }

    for (int s = 0; s < CHUNK; ++s) {
        const float dav = dAs[s];
        const float xv  = xs[s][p];
        const float xh  = dts[s] * xv;
        const float4* Bp = (const float4*)&Bsh[s][nq * 16];
        const float4* Cp = (const float4*)&Csh[s][nq * 16];
        float yp = 0.f;
#pragma unroll
        for (int g = 0; g < 4; ++g) {
            const float4 bv = Bp[g];
            const float4 cv = Cp[g];
            st[g * 4 + 0] = fmaf(st[g * 4 + 0], dav, xh * bv.x); yp = fmaf(st[g * 4 + 0], cv.x, yp);
            st[g * 4 + 1] = fmaf(st[g * 4 + 1], dav, xh * bv.y); yp = fmaf(st[g * 4 + 1], cv.y, yp);
            st[g * 4 + 2] = fmaf(st[g * 4 + 2], dav, xh * bv.z); yp = fmaf(st[g * 4 + 2], cv.z, yp);
            st[g * 4 + 3] = fmaf(st[g * 4 + 3], dav, xh * bv.w); yp = fmaf(st[g * 4 + 3], cv.w, yp);
        }
        yp += __shfl_xor(yp, 1);
        yp += __shfl_xor(yp, 2);
        if (nq == 0)
            conv[(row0 + s) * CONVDIM + h * 64 + p] = yp + dpv * xv;
    }
}

// ---------------- y*silu(z) -> rmsnorm (D=512) -> bf16 yzn ----------------
__global__ __launch_bounds__(256) void gate_norm_kernel(const float* __restrict__ convp,
                                                        const float* __restrict__ zx,
                                                        const float* __restrict__ gw,
                                                        short* __restrict__ yzn) {
    const int row  = blockIdx.x * 4 + (threadIdx.x >> 6);
    const int lane = threadIdx.x & 63;
    const float* yrow = convp + (size_t)row * CONVDIM + lane * 8;
    const float* zrow = zx + (size_t)row * DPROJ + lane * 8;
    const float4 y0 = *(const float4*)(yrow);
    const float4 y1 = *(const float4*)(yrow + 4);
    const float4 z0 = *(const float4*)(zrow);
    const float4 z1 = *(const float4*)(zrow + 4);
    float v[8];
    v[0] = y0.x * z0.x / (1.f + __expf(-z0.x));
    v[1] = y0.y * z0.y / (1.f + __expf(-z0.y));
    v[2] = y0.z * z0.z / (1.f + __expf(-z0.z));
    v[3] = y0.w * z0.w / (1.f + __expf(-z0.w));
    v[4] = y1.x * z1.x / (1.f + __expf(-z1.x));
    v[5] = y1.y * z1.y / (1.f + __expf(-z1.y));
    v[6] = y1.z * z1.z / (1.f + __expf(-z1.z));
    v[7] = y1.w * z1.w / (1.f + __expf(-z1.w));
    float ss = 0.f;
#pragma unroll
    for (int i = 0; i < 8; ++i) ss += v[i] * v[i];
#pragma unroll
    for (int off = 1; off < 64; off <<= 1) ss += __shfl_xor(ss, off);
    const float rs = rsqrtf(ss * (1.0f / DINNER) + 1e-5f);
    const float* g = gw + lane * 8;
    short8v o;
#pragma unroll
    for (int i = 0; i < 8; ++i) o[i] = f2bf(v[i] * rs * g[i]);
    *(short8v*)(yzn + (size_t)row * DINNER + lane * 8) = o;
}

// ---------------- launch ----------------
extern "C" void kernel_launch(void* const* d_in, const int* in_sizes, int n_in,
                              void* d_out, int out_size, void* d_ws, size_t ws_size,
                              hipStream_t stream) {
    (void)in_sizes; (void)n_in; (void)out_size; (void)d_ws; (void)ws_size;
    const float* x      = (const float*)d_in[0];
    const float* W_in   = (const float*)d_in[1];
    const float* conv_w = (const float*)d_in[2];
    const float* conv_b = (const float*)d_in[3];
    const float* dt_b   = (const float*)d_in[4];
    const float* A_log  = (const float*)d_in[5];
    const float* Dp     = (const float*)d_in[6];
    const float* g_w    = (const float*)d_in[7];
    const float* n_w    = (const float*)d_in[8];
    const float* W_out  = (const float*)d_in[9];
    float* out = (float*)d_out;

    short *xn, *yzn, *winb, *woutb;
    float *zx, *cv, *lst, *dcy;
    hipGetSymbolAddress((void**)&xn,    HIP_SYMBOL(g_xn));
    hipGetSymbolAddress((void**)&zx,    HIP_SYMBOL(g_zx));
    hipGetSymbolAddress((void**)&cv,    HIP_SYMBOL(g_conv));
    hipGetSymbolAddress((void**)&yzn,   HIP_SYMBOL(g_yzn));
    hipGetSymbolAddress((void**)&lst,   HIP_SYMBOL(g_lstate));
    hipGetSymbolAddress((void**)&dcy,   HIP_SYMBOL(g_decayC));
    hipGetSymbolAddress((void**)&winb,  HIP_SYMBOL(g_Winb));
    hipGetSymbolAddress((void**)&woutb, HIP_SYMBOL(g_Woutb));

    convert_bf16_kernel<<<(NPAD * DMODEL) / 256, 256, 0, stream>>>(
        W_in, winb, DPROJ * DMODEL, NPAD * DMODEL);
    convert_bf16_kernel<<<(DMODEL * DINNER) / 256, 256, 0, stream>>>(
        W_out, woutb, DMODEL * DINNER, DMODEL * DINNER);

    rmsnorm_x_kernel<<<NROWS / 4, 256, 0, stream>>>(x, n_w, xn);

    gemm_bf16_nt<false><<<dim3(NPAD / 128, NROWS / 128), 256, 0, stream>>>(
        xn, winb, nullptr, zx, NROWS, DPROJ, DMODEL);

    dt_fix_kernel<<<NROWS / 4, 256, 0, stream>>>(x, n_w, W_in, zx);

    conv_silu_kernel<<<(NROWS * CONVDIM) / 256, 256, 0, stream>>>(zx, conv_w, conv_b, cv);

    chunk_state_kernel<<<BATCH * NHEADS * NCHUNK, 256, 0, stream>>>(zx, cv, dt_b, A_log, lst, dcy);
    state_prefix_kernel<<<(BATCH * NHEADS * HEADDIM * DSTATE) / 256, 256, 0, stream>>>(lst, dcy);
    chunk_scan_kernel<<<BATCH * NHEADS * NCHUNK, 256, 0, stream>>>(zx, cv, dt_b, A_log, Dp, lst);

    gate_norm_kernel<<<NROWS / 4, 256, 0, stream>>>(cv, zx, g_w, yzn);

    gemm_bf16_nt<true><<<dim3(DMODEL / 128, NROWS / 128), 256, 0, stream>>>(
        yzn, woutb, x, out, NROWS, DMODEL, DINNER);
}

// Round 4
// 360.489 us; speedup vs baseline: 4.9036x; 1.3441x over previous
//
#include <hip/hip_runtime.h>
#include <math.h>

#define BATCH   8
#define SEQ     4096
#define DMODEL  256
#define DINNER  512
#define DSTATE  64
#define NHEADS  8
#define HEADDIM 64
#define CONVDIM 640          // DINNER + 2*DSTATE
#define DPROJ   1160         // 2*DINNER + 2*DSTATE + NHEADS
#define NROWS   (BATCH*SEQ)  // 32768
#define CHUNK   64
#define NCHUNK  (SEQ/CHUNK)  // 64
#define NPAD    1280         // DPROJ padded to mult of 128 for bf16 W_in
#define LSTR    72           // LDS row stride (shorts): 144B rows -> 16B aligned, ~2-way banks

typedef short bf16x8 __attribute__((ext_vector_type(8)));
typedef short short8v __attribute__((ext_vector_type(8)));
typedef float f32x4 __attribute__((ext_vector_type(4)));

// ---- static workspace (BSS, allocated at module load; ws_size-independent) ----
__device__ short g_xn[(size_t)NROWS * DMODEL];     // bf16 16.8 MB
__device__ float g_zx[(size_t)NROWS * DPROJ];      // 152.0 MB
__device__ float g_conv[(size_t)NROWS * CONVDIM];  //  83.9 MB (x part overwritten by y)
__device__ short g_yzn[(size_t)NROWS * DINNER];    // bf16 33.5 MB
__device__ short g_lstate[(size_t)BATCH * NHEADS * NCHUNK * HEADDIM * DSTATE]; // bf16 33.5 MB
__device__ float g_decayC[BATCH * NHEADS * NCHUNK];
__device__ short g_Winb[(size_t)NPAD * DMODEL];    // bf16 W_in, zero-padded rows
__device__ short g_Woutb[(size_t)DMODEL * DINNER]; // bf16 W_out

__device__ __forceinline__ short f2bf(float f) {   // RNE fp32 -> bf16
    unsigned u = __float_as_uint(f);
    u += 0x7fff + ((u >> 16) & 1);
    return (short)(u >> 16);
}
__device__ __forceinline__ float bf2f(short s) {
    return __uint_as_float(((unsigned)(unsigned short)s) << 16);
}

__device__ __forceinline__ void stage16(const void* gsrc, void* ldst) {
    __builtin_amdgcn_global_load_lds(
        (const __attribute__((address_space(1))) void*)gsrc,
        (__attribute__((address_space(3))) void*)ldst, 16, 0, 0);
}

// ---------------- weight convert: fp32 -> bf16 with flat zero-pad tail ----------------
__global__ __launch_bounds__(256) void convert_bf16_kernel(const float* __restrict__ src,
                                                           short* __restrict__ dst,
                                                           int n_valid, int n_total) {
    const int i = blockIdx.x * 256 + threadIdx.x;
    if (i < n_total) dst[i] = (i < n_valid) ? f2bf(src[i]) : (short)0;
}

// ---------------- kernel 1: rmsnorm of x (D=256) -> bf16, one wave per row ----------------
__global__ __launch_bounds__(256) void rmsnorm_x_kernel(const float* __restrict__ x,
                                                        const float* __restrict__ w,
                                                        short* __restrict__ xn) {
    const int row  = blockIdx.x * 4 + (threadIdx.x >> 6);
    const int lane = threadIdx.x & 63;
    const float4 v = *(const float4*)(x + (size_t)row * DMODEL + lane * 4);
    float ss = v.x * v.x + v.y * v.y + v.z * v.z + v.w * v.w;
#pragma unroll
    for (int off = 1; off < 64; off <<= 1) ss += __shfl_xor(ss, off);
    const float rs = rsqrtf(ss * (1.0f / DMODEL) + 1.1920929e-7f);
    const float4 wv = *(const float4*)(w + lane * 4);
    short4 o;
    o.x = f2bf(v.x * rs * wv.x); o.y = f2bf(v.y * rs * wv.y);
    o.z = f2bf(v.z * rs * wv.z); o.w = f2bf(v.w * rs * wv.w);
    *(short4*)(xn + (size_t)row * DMODEL + lane * 4) = o;
}

// ---------------- bf16 MFMA GEMM (m97 structure): C[M][N] = A[M][K] * B[N][K]^T ----------
template <bool RES>
__global__ __launch_bounds__(256) void gemm_bf16_nt(const short* __restrict__ A,
                                                    const short* __restrict__ B,
                                                    const float* __restrict__ R,
                                                    float* __restrict__ C,
                                                    int M, int N, int K) {
    __shared__ __align__(16) short Asl[128 * 32];
    __shared__ __align__(16) short Bsl[128 * 32];
    const int tid  = threadIdx.x;
    const int lane = tid & 63;
    const int wid  = tid >> 6;
    const int m0 = blockIdx.y * 128, n0 = blockIdx.x * 128;
    const int wrow = (wid >> 1) * 64, wcol = (wid & 1) * 64;

    f32x4 acc[4][4];
#pragma unroll
    for (int m = 0; m < 4; ++m)
#pragma unroll
        for (int n = 0; n < 4; ++n) acc[m][n] = (f32x4)0.f;

    const int wbase = (tid & 0xC0) * 8;

    for (int k0 = 0; k0 < K; k0 += 32) {
#pragma unroll
        for (int r = 0; r < 2; ++r) {
            const int idx = r * 256 + tid;
            const int row = idx >> 2;
            const int ko  = (idx & 3) * 8;
            stage16(A + (size_t)(m0 + row) * K + k0 + ko, Asl + r * 2048 + wbase);
            stage16(B + (size_t)(n0 + row) * K + k0 + ko, Bsl + r * 2048 + wbase);
        }
        __syncthreads();
        bf16x8 af[4], bfr[4];
#pragma unroll
        for (int m = 0; m < 4; ++m)
            af[m] = *(const bf16x8*)(Asl + (wrow + m * 16 + (lane & 15)) * 32 + (lane >> 4) * 8);
#pragma unroll
        for (int n = 0; n < 4; ++n)
            bfr[n] = *(const bf16x8*)(Bsl + (wcol + n * 16 + (lane & 15)) * 32 + (lane >> 4) * 8);
#pragma unroll
        for (int m = 0; m < 4; ++m)
#pragma unroll
            for (int n = 0; n < 4; ++n)
                acc[m][n] = __builtin_amdgcn_mfma_f32_16x16x32_bf16(af[m], bfr[n], acc[m][n], 0, 0, 0);
        __syncthreads();
    }

    const int r0 = (lane >> 4) * 4;
#pragma unroll
    for (int m = 0; m < 4; ++m) {
        const int grow = m0 + wrow + m * 16 + r0;
#pragma unroll
        for (int n = 0; n < 4; ++n) {
            const int gcol = n0 + wcol + n * 16 + (lane & 15);
            if (gcol < N) {
#pragma unroll
                for (int reg = 0; reg < 4; ++reg) {
                    float v = acc[m][n][reg];
                    if (RES) v += R[(size_t)(grow + reg) * N + gcol];
                    C[(size_t)(grow + reg) * N + gcol] = v;
                }
            }
        }
    }
}

// ---------------- dt fixup: recompute the 8 dt columns of zx in fp32 ----------------
__global__ __launch_bounds__(256) void dt_fix_kernel(const float* __restrict__ x,
                                                     const float* __restrict__ nw,
                                                     const float* __restrict__ W_in,
                                                     float* __restrict__ zx) {
    const int row  = blockIdx.x * 4 + (threadIdx.x >> 6);
    const int lane = threadIdx.x & 63;
    const float4 v = *(const float4*)(x + (size_t)row * DMODEL + lane * 4);
    float ss = v.x * v.x + v.y * v.y + v.z * v.z + v.w * v.w;
#pragma unroll
    for (int off = 1; off < 64; off <<= 1) ss += __shfl_xor(ss, off);
    const float rs = rsqrtf(ss * (1.0f / DMODEL) + 1.1920929e-7f);
    const float4 wv = *(const float4*)(nw + lane * 4);
    const float4 xn4 = make_float4(v.x * rs * wv.x, v.y * rs * wv.y,
                                   v.z * rs * wv.z, v.w * rs * wv.w);
#pragma unroll
    for (int h = 0; h < NHEADS; ++h) {
        const float4 ww = *(const float4*)(W_in + (size_t)(DPROJ - NHEADS + h) * DMODEL + lane * 4);
        float p = xn4.x * ww.x + xn4.y * ww.y + xn4.z * ww.z + xn4.w * ww.w;
#pragma unroll
        for (int off = 1; off < 64; off <<= 1) p += __shfl_xor(p, off);
        if (lane == 0) zx[(size_t)row * DPROJ + (DPROJ - NHEADS) + h] = p;
    }
}

// ---------------- depthwise causal conv(4) + bias + SiLU ----------------
__global__ __launch_bounds__(256) void conv_silu_kernel(const float* __restrict__ zx,
                                                        const float* __restrict__ cw,
                                                        const float* __restrict__ cb,
                                                        float* __restrict__ outp) {
    const int idx = blockIdx.x * 256 + threadIdx.x;
    const int c  = idx % CONVDIM;
    const int bl = idx / CONVDIM;
    const int l  = bl & (SEQ - 1);
    const float* src = zx + (size_t)bl * DPROJ + DINNER + c;
    float s = cb[c];
#pragma unroll
    for (int k = 0; k < 4; ++k) {
        const int ls = l + k - 3;
        if (ls >= 0) s = fmaf(src[(ptrdiff_t)(k - 3) * DPROJ], cw[c * 4 + k], s);
    }
    outp[idx] = s / (1.f + __expf(-s));
}

// ---------------- scan pass 1 (MFMA): L[p][n] = sum_t X[t][p] * (w_t * B[t][n]) ----------
// w_t = exp(aneg*(cum63-cum_t)) * dt_t. One block per (b,h,c); 4 waves, wave owns 16 p-rows.
__global__ __launch_bounds__(256) void chunk_state_mfma(const float* __restrict__ zx,
                                                        const float* __restrict__ conv,
                                                        const float* __restrict__ dt_bias,
                                                        const float* __restrict__ A_log,
                                                        short* __restrict__ lstate,
                                                        float* __restrict__ decayC) {
    const int bhc = blockIdx.x;
    const int c = bhc & (NCHUNK - 1), bh = bhc >> 6, h = bh & (NHEADS - 1), b = bh >> 3;
    const int tid = threadIdx.x, lane = tid & 63, wid = tid >> 6;
    __shared__ short XT[64 * LSTR];   // XT[p][t]
    __shared__ short BT[64 * LSTR];   // (w*B)^T [n][t]
    __shared__ float wsh[CHUNK];
    const size_t row0 = (size_t)b * SEQ + (size_t)c * CHUNK;

    const float aneg  = -__expf(A_log[h]);
    const float dbias = dt_bias[h];
    if (tid < 64) {
        const float draw = zx[(row0 + tid) * DPROJ + (DPROJ - NHEADS) + h] + dbias;
        const float dtv  = (draw > 20.f) ? draw : log1pf(__expf(draw));
        float cum = aneg * dtv;
#pragma unroll
        for (int off = 1; off < 64; off <<= 1) {
            const float nv = __shfl_up(cum, off);
            if (lane >= off) cum += nv;
        }
        const float total = __shfl(cum, 63);
        wsh[tid] = __expf(total - cum) * dtv;
        if (tid == 63) decayC[bhc] = __expf(cum);
    }
    __syncthreads();

#pragma unroll
    for (int r = 0; r < 4; ++r) {
        const int idx  = tid + r * 256;
        const int trow = idx >> 4;
        const int c4   = (idx & 15) * 4;
        const float* rp = conv + (row0 + trow) * CONVDIM;
        const float4 xv = *(const float4*)(rp + h * 64 + c4);
        const float4 bv = *(const float4*)(rp + DINNER + c4);
        const float w = wsh[trow];
        XT[(c4 + 0) * LSTR + trow] = f2bf(xv.x);
        XT[(c4 + 1) * LSTR + trow] = f2bf(xv.y);
        XT[(c4 + 2) * LSTR + trow] = f2bf(xv.z);
        XT[(c4 + 3) * LSTR + trow] = f2bf(xv.w);
        BT[(c4 + 0) * LSTR + trow] = f2bf(bv.x * w);
        BT[(c4 + 1) * LSTR + trow] = f2bf(bv.y * w);
        BT[(c4 + 2) * LSTR + trow] = f2bf(bv.z * w);
        BT[(c4 + 3) * LSTR + trow] = f2bf(bv.w * w);
    }
    __syncthreads();

    f32x4 acc[4];
#pragma unroll
    for (int n = 0; n < 4; ++n) acc[n] = (f32x4)0.f;
#pragma unroll
    for (int ks = 0; ks < 2; ++ks) {
        const bf16x8 af = *(const bf16x8*)(XT + (wid * 16 + (lane & 15)) * LSTR + ks * 32 + (lane >> 4) * 8);
#pragma unroll
        for (int n = 0; n < 4; ++n) {
            const bf16x8 bfv = *(const bf16x8*)(BT + (n * 16 + (lane & 15)) * LSTR + ks * 32 + (lane >> 4) * 8);
            acc[n] = __builtin_amdgcn_mfma_f32_16x16x32_bf16(af, bfv, acc[n], 0, 0, 0);
        }
    }
    short* lp = lstate + ((size_t)bhc << 12);
#pragma unroll
    for (int n = 0; n < 4; ++n)
#pragma unroll
        for (int reg = 0; reg < 4; ++reg) {
            const int p = wid * 16 + (lane >> 4) * 4 + reg;
            lp[p * 64 + n * 16 + (lane & 15)] = f2bf(acc[n][reg]);
        }
}

// ---------------- scan pass 2: inter-chunk recurrence on bf16 lstate (fp32 carry) --------
__global__ __launch_bounds__(256) void state_prefix_kernel(short* __restrict__ lstate,
                                                           const float* __restrict__ decayC) {
    const int idx = blockIdx.x * 256 + threadIdx.x;   // over BATCH*NHEADS*4096
    const int bh = idx >> 12;
    const int pn = idx & 4095;
    float S = 0.f;
    for (int c = 0; c < NCHUNK; ++c) {
        short* ptr = lstate + (((size_t)bh * NCHUNK + c) << 12) + pn;
        const float l = bf2f(*ptr);
        *ptr = f2bf(S);
        S = fmaf(S, decayC[bh * NCHUNK + c], l);
    }
}

// ---------------- scan pass 3 (MFMA): Y = mask(C@B^T)@X + exp(cum)*(C@SP^T) + Dp*X --------
__global__ __launch_bounds__(256) void chunk_scan_mfma(const float* __restrict__ zx,
                                                       float* __restrict__ conv,
                                                       const float* __restrict__ dt_bias,
                                                       const float* __restrict__ A_log,
                                                       const float* __restrict__ Dp,
                                                       const short* __restrict__ lstate) {
    const int bhc = blockIdx.x;
    const int c = bhc & (NCHUNK - 1), bh = bhc >> 6, h = bh & (NHEADS - 1), b = bh >> 3;
    const int tid = threadIdx.x, lane = tid & 63, wid = tid >> 6;
    __shared__ short Bs[64 * LSTR];   // B rows [t][n]
    __shared__ short Cs[64 * LSTR];   // C rows [s][n]
    __shared__ short XT[64 * LSTR];   // X^T [p][t]
    __shared__ short SP[64 * LSTR];   // prefix state rows [p][n]
    __shared__ short Ms[64 * LSTR];   // masked scores rows [s][t]
    __shared__ float cums[CHUNK];
    __shared__ float dtss[CHUNK];
    const size_t row0 = (size_t)b * SEQ + (size_t)c * CHUNK;

    // stage B, C row-major; X transposed
#pragma unroll
    for (int r = 0; r < 4; ++r) {
        const int idx  = tid + r * 256;
        const int trow = idx >> 4;
        const int c4   = (idx & 15) * 4;
        const float* rp = conv + (row0 + trow) * CONVDIM;
        const float4 xv = *(const float4*)(rp + h * 64 + c4);
        const float4 bv = *(const float4*)(rp + DINNER + c4);
        const float4 cv = *(const float4*)(rp + DINNER + DSTATE + c4);
        short4 b4; b4.x = f2bf(bv.x); b4.y = f2bf(bv.y); b4.z = f2bf(bv.z); b4.w = f2bf(bv.w);
        short4 c4v; c4v.x = f2bf(cv.x); c4v.y = f2bf(cv.y); c4v.z = f2bf(cv.z); c4v.w = f2bf(cv.w);
        *(short4*)(Bs + trow * LSTR + c4) = b4;
        *(short4*)(Cs + trow * LSTR + c4) = c4v;
        XT[(c4 + 0) * LSTR + trow] = f2bf(xv.x);
        XT[(c4 + 1) * LSTR + trow] = f2bf(xv.y);
        XT[(c4 + 2) * LSTR + trow] = f2bf(xv.z);
        XT[(c4 + 3) * LSTR + trow] = f2bf(xv.w);
    }
    // stage prefix state (bf16 rows [p][n], contiguous copy)
#pragma unroll
    for (int r = 0; r < 2; ++r) {
        const int idx = tid + r * 256;
        const int p = idx >> 3, n8 = (idx & 7) * 8;
        *(short8v*)(SP + p * LSTR + n8) =
            *(const short8v*)(lstate + ((size_t)bhc << 12) + p * 64 + n8);
    }
    const float aneg  = -__expf(A_log[h]);
    const float dbias = dt_bias[h];
    if (tid < 64) {
        const float draw = zx[(row0 + tid) * DPROJ + (DPROJ - NHEADS) + h] + dbias;
        const float dtv  = (draw > 20.f) ? draw : log1pf(__expf(draw));
        float cum = aneg * dtv;
#pragma unroll
        for (int off = 1; off < 64; off <<= 1) {
            const float nv = __shfl_up(cum, off);
            if (lane >= off) cum += nv;
        }
        cums[tid] = cum;
        dtss[tid] = dtv;
    }
    __syncthreads();

    // G = C @ B^T (over n)
    f32x4 accG[4];
#pragma unroll
    for (int tf = 0; tf < 4; ++tf) accG[tf] = (f32x4)0.f;
#pragma unroll
    for (int ks = 0; ks < 2; ++ks) {
        const bf16x8 af = *(const bf16x8*)(Cs + (wid * 16 + (lane & 15)) * LSTR + ks * 32 + (lane >> 4) * 8);
#pragma unroll
        for (int tf = 0; tf < 4; ++tf) {
            const bf16x8 bfv = *(const bf16x8*)(Bs + (tf * 16 + (lane & 15)) * LSTR + ks * 32 + (lane >> 4) * 8);
            accG[tf] = __builtin_amdgcn_mfma_f32_16x16x32_bf16(af, bfv, accG[tf], 0, 0, 0);
        }
    }
    // causal mask + decay scale -> Ms (bf16)
    const int srow0 = wid * 16 + (lane >> 4) * 4;
#pragma unroll
    for (int tf = 0; tf < 4; ++tf) {
        const int t = tf * 16 + (lane & 15);
        const float ct  = cums[t];
        const float dtt = dtss[t];
#pragma unroll
        for (int reg = 0; reg < 4; ++reg) {
            const int s = srow0 + reg;
            const float m = (t <= s) ? accG[tf][reg] * __expf(cums[s] - ct) * dtt : 0.f;
            Ms[s * LSTR + t] = f2bf(m);
        }
    }
    __syncthreads();

    // Y1 = M @ X (B-op = XT rows p over k=t); Y2 = C @ SP^T (B-op = SP rows p over k=n)
    f32x4 acc1[4], acc2[4];
#pragma unroll
    for (int pf = 0; pf < 4; ++pf) { acc1[pf] = (f32x4)0.f; acc2[pf] = (f32x4)0.f; }
#pragma unroll
    for (int ks = 0; ks < 2; ++ks) {
        const bf16x8 am = *(const bf16x8*)(Ms + (wid * 16 + (lane & 15)) * LSTR + ks * 32 + (lane >> 4) * 8);
        const bf16x8 ac = *(const bf16x8*)(Cs + (wid * 16 + (lane & 15)) * LSTR + ks * 32 + (lane >> 4) * 8);
#pragma unroll
        for (int pf = 0; pf < 4; ++pf) {
            const bf16x8 bx = *(const bf16x8*)(XT + (pf * 16 + (lane & 15)) * LSTR + ks * 32 + (lane >> 4) * 8);
            const bf16x8 bs = *(const bf16x8*)(SP + (pf * 16 + (lane & 15)) * LSTR + ks * 32 + (lane >> 4) * 8);
            acc1[pf] = __builtin_amdgcn_mfma_f32_16x16x32_bf16(am, bx, acc1[pf], 0, 0, 0);
            acc2[pf] = __builtin_amdgcn_mfma_f32_16x16x32_bf16(ac, bs, acc2[pf], 0, 0, 0);
        }
    }
    const float dpv = Dp[h];
    float es[4];
#pragma unroll
    for (int reg = 0; reg < 4; ++reg) es[reg] = __expf(cums[srow0 + reg]);
#pragma unroll
    for (int pf = 0; pf < 4; ++pf) {
        const int p = pf * 16 + (lane & 15);
#pragma unroll
        for (int reg = 0; reg < 4; ++reg) {
            const int s = srow0 + reg;
            const float xv = bf2f(XT[p * LSTR + s]);
            conv[(row0 + s) * CONVDIM + h * 64 + p] =
                acc1[pf][reg] + es[reg] * acc2[pf][reg] + dpv * xv;
        }
    }
}

// ---------------- y*silu(z) -> rmsnorm (D=512) -> bf16 yzn ----------------
__global__ __launch_bounds__(256) void gate_norm_kernel(const float* __restrict__ convp,
                                                        const float* __restrict__ zx,
                                                        const float* __restrict__ gw,
                                                        short* __restrict__ yzn) {
    const int row  = blockIdx.x * 4 + (threadIdx.x >> 6);
    const int lane = threadIdx.x & 63;
    const float* yrow = convp + (size_t)row * CONVDIM + lane * 8;
    const float* zrow = zx + (size_t)row * DPROJ + lane * 8;
    const float4 y0 = *(const float4*)(yrow);
    const float4 y1 = *(const float4*)(yrow + 4);
    const float4 z0 = *(const float4*)(zrow);
    const float4 z1 = *(const float4*)(zrow + 4);
    float v[8];
    v[0] = y0.x * z0.x / (1.f + __expf(-z0.x));
    v[1] = y0.y * z0.y / (1.f + __expf(-z0.y));
    v[2] = y0.z * z0.z / (1.f + __expf(-z0.z));
    v[3] = y0.w * z0.w / (1.f + __expf(-z0.w));
    v[4] = y1.x * z1.x / (1.f + __expf(-z1.x));
    v[5] = y1.y * z1.y / (1.f + __expf(-z1.y));
    v[6] = y1.z * z1.z / (1.f + __expf(-z1.z));
    v[7] = y1.w * z1.w / (1.f + __expf(-z1.w));
    float ss = 0.f;
#pragma unroll
    for (int i = 0; i < 8; ++i) ss += v[i] * v[i];
#pragma unroll
    for (int off = 1; off < 64; off <<= 1) ss += __shfl_xor(ss, off);
    const float rs = rsqrtf(ss * (1.0f / DINNER) + 1e-5f);
    const float* g = gw + lane * 8;
    short8v o;
#pragma unroll
    for (int i = 0; i < 8; ++i) o[i] = f2bf(v[i] * rs * g[i]);
    *(short8v*)(yzn + (size_t)row * DINNER + lane * 8) = o;
}

// ---------------- launch ----------------
extern "C" void kernel_launch(void* const* d_in, const int* in_sizes, int n_in,
                              void* d_out, int out_size, void* d_ws, size_t ws_size,
                              hipStream_t stream) {
    (void)in_sizes; (void)n_in; (void)out_size; (void)d_ws; (void)ws_size;
    const float* x      = (const float*)d_in[0];
    const float* W_in   = (const float*)d_in[1];
    const float* conv_w = (const float*)d_in[2];
    const float* conv_b = (const float*)d_in[3];
    const float* dt_b   = (const float*)d_in[4];
    const float* A_log  = (const float*)d_in[5];
    const float* Dp     = (const float*)d_in[6];
    const float* g_w    = (const float*)d_in[7];
    const float* n_w    = (const float*)d_in[8];
    const float* W_out  = (const float*)d_in[9];
    float* out = (float*)d_out;

    short *xn, *yzn, *winb, *woutb, *lst;
    float *zx, *cv, *dcy;
    hipGetSymbolAddress((void**)&xn,    HIP_SYMBOL(g_xn));
    hipGetSymbolAddress((void**)&zx,    HIP_SYMBOL(g_zx));
    hipGetSymbolAddress((void**)&cv,    HIP_SYMBOL(g_conv));
    hipGetSymbolAddress((void**)&yzn,   HIP_SYMBOL(g_yzn));
    hipGetSymbolAddress((void**)&lst,   HIP_SYMBOL(g_lstate));
    hipGetSymbolAddress((void**)&dcy,   HIP_SYMBOL(g_decayC));
    hipGetSymbolAddress((void**)&winb,  HIP_SYMBOL(g_Winb));
    hipGetSymbolAddress((void**)&woutb, HIP_SYMBOL(g_Woutb));

    convert_bf16_kernel<<<(NPAD * DMODEL) / 256, 256, 0, stream>>>(
        W_in, winb, DPROJ * DMODEL, NPAD * DMODEL);
    convert_bf16_kernel<<<(DMODEL * DINNER) / 256, 256, 0, stream>>>(
        W_out, woutb, DMODEL * DINNER, DMODEL * DINNER);

    rmsnorm_x_kernel<<<NROWS / 4, 256, 0, stream>>>(x, n_w, xn);

    gemm_bf16_nt<false><<<dim3(NPAD / 128, NROWS / 128), 256, 0, stream>>>(
        xn, winb, nullptr, zx, NROWS, DPROJ, DMODEL);

    dt_fix_kernel<<<NROWS / 4, 256, 0, stream>>>(x, n_w, W_in, zx);

    conv_silu_kernel<<<(NROWS * CONVDIM) / 256, 256, 0, stream>>>(zx, conv_w, conv_b, cv);

    chunk_state_mfma<<<BATCH * NHEADS * NCHUNK, 256, 0, stream>>>(zx, cv, dt_b, A_log, lst, dcy);
    state_prefix_kernel<<<(BATCH * NHEADS * HEADDIM * DSTATE) / 256, 256, 0, stream>>>(lst, dcy);
    chunk_scan_mfma<<<BATCH * NHEADS * NCHUNK, 256, 0, stream>>>(zx, cv, dt_b, A_log, Dp, lst);

    gate_norm_kernel<<<NROWS / 4, 256, 0, stream>>>(cv, zx, g_w, yzn);

    gemm_bf16_nt<true><<<dim3(DMODEL / 128, NROWS / 128), 256, 0, stream>>>(
        yzn, woutb, x, out, NROWS, DMODEL, DINNER);
}

// Round 5
// 319.301 us; speedup vs baseline: 5.5361x; 1.1290x over previous
//
#include <hip/hip_runtime.h>
#include <math.h>

#define BATCH   8
#define SEQ     4096
#define DMODEL  256
#define DINNER  512
#define DSTATE  64
#define NHEADS  8
#define HEADDIM 64
#define CONVDIM 640          // DINNER + 2*DSTATE
#define DPROJ   1160         // 2*DINNER + 2*DSTATE + NHEADS
#define NROWS   (BATCH*SEQ)  // 32768
#define CHUNK   64
#define NCHUNK  (SEQ/CHUNK)  // 64
#define NPAD    1280         // DPROJ padded to mult of 128 for bf16 W_in
#define LSTR    72           // LDS row stride (shorts)

typedef short bf16x8 __attribute__((ext_vector_type(8)));
typedef short short8v __attribute__((ext_vector_type(8)));
typedef float f32x4 __attribute__((ext_vector_type(4)));

// ---- static workspace (BSS) ----
__device__ short g_xn[(size_t)NROWS * DMODEL];      // bf16 16.8 MB
__device__ short g_zxb[(size_t)NROWS * DPROJ];      // bf16 76.0 MB (z | xBC | unused dt)
__device__ short g_xbc[(size_t)NROWS * CONVDIM];    // bf16 42.0 MB (conv+silu output)
__device__ float g_y[(size_t)NROWS * DINNER];       // fp32 67.1 MB (scan output)
__device__ float g_dt[(size_t)NROWS * NHEADS];      // fp32  1.0 MB (raw dt, pre-bias)
__device__ short g_yzn[(size_t)NROWS * DINNER];     // bf16 33.5 MB
__device__ short g_lstate[(size_t)BATCH * NHEADS * NCHUNK * HEADDIM * DSTATE]; // bf16 33.5 MB
__device__ float g_decayC[BATCH * NHEADS * NCHUNK];
__device__ short g_Winb[(size_t)NPAD * DMODEL];     // bf16 W_in, zero-padded rows
__device__ short g_Woutb[(size_t)DMODEL * DINNER];  // bf16 W_out

__device__ __forceinline__ short f2bf(float f) {
    unsigned u = __float_as_uint(f);
    u += 0x7fff + ((u >> 16) & 1);
    return (short)(u >> 16);
}
__device__ __forceinline__ float bf2f(short s) {
    return __uint_as_float(((unsigned)(unsigned short)s) << 16);
}

__device__ __forceinline__ void stage16(const void* gsrc, void* ldst) {
    __builtin_amdgcn_global_load_lds(
        (const __attribute__((address_space(1))) void*)gsrc,
        (__attribute__((address_space(3))) void*)ldst, 16, 0, 0);
}

// ---------------- weight convert: fp32 -> bf16 with flat zero-pad tail ----------------
__global__ __launch_bounds__(256) void convert_bf16_kernel(const float* __restrict__ src,
                                                           short* __restrict__ dst,
                                                           int n_valid, int n_total) {
    const int i = blockIdx.x * 256 + threadIdx.x;
    if (i < n_total) dst[i] = (i < n_valid) ? f2bf(src[i]) : (short)0;
}

// ---------------- rmsnorm of x (D=256) -> bf16 ----------------
__global__ __launch_bounds__(256) void rmsnorm_x_kernel(const float* __restrict__ x,
                                                        const float* __restrict__ w,
                                                        short* __restrict__ xn) {
    const int row  = blockIdx.x * 4 + (threadIdx.x >> 6);
    const int lane = threadIdx.x & 63;
    const float4 v = *(const float4*)(x + (size_t)row * DMODEL + lane * 4);
    float ss = v.x * v.x + v.y * v.y + v.z * v.z + v.w * v.w;
#pragma unroll
    for (int off = 1; off < 64; off <<= 1) ss += __shfl_xor(ss, off);
    const float rs = rsqrtf(ss * (1.0f / DMODEL) + 1.1920929e-7f);
    const float4 wv = *(const float4*)(w + lane * 4);
    short4 o;
    o.x = f2bf(v.x * rs * wv.x); o.y = f2bf(v.y * rs * wv.y);
    o.z = f2bf(v.z * rs * wv.z); o.w = f2bf(v.w * rs * wv.w);
    *(short4*)(xn + (size_t)row * DMODEL + lane * 4) = o;
}

// ---------------- bf16 MFMA GEMM: C[M][N] = A[M][K] * B[N][K]^T ----------
// OUT=short -> bf16 store; OUT=float -> fp32 (+optional residual).
template <bool RES, typename OUT>
__global__ __launch_bounds__(256) void gemm_bf16_nt(const short* __restrict__ A,
                                                    const short* __restrict__ B,
                                                    const float* __restrict__ R,
                                                    OUT* __restrict__ C,
                                                    int M, int N, int K) {
    __shared__ __align__(16) short Asl[128 * 32];
    __shared__ __align__(16) short Bsl[128 * 32];
    const int tid  = threadIdx.x;
    const int lane = tid & 63;
    const int wid  = tid >> 6;
    const int m0 = blockIdx.y * 128, n0 = blockIdx.x * 128;
    const int wrow = (wid >> 1) * 64, wcol = (wid & 1) * 64;

    f32x4 acc[4][4];
#pragma unroll
    for (int m = 0; m < 4; ++m)
#pragma unroll
        for (int n = 0; n < 4; ++n) acc[m][n] = (f32x4)0.f;

    const int wbase = (tid & 0xC0) * 8;

    for (int k0 = 0; k0 < K; k0 += 32) {
#pragma unroll
        for (int r = 0; r < 2; ++r) {
            const int idx = r * 256 + tid;
            const int row = idx >> 2;
            const int ko  = (idx & 3) * 8;
            stage16(A + (size_t)(m0 + row) * K + k0 + ko, Asl + r * 2048 + wbase);
            stage16(B + (size_t)(n0 + row) * K + k0 + ko, Bsl + r * 2048 + wbase);
        }
        __syncthreads();
        bf16x8 af[4], bfr[4];
#pragma unroll
        for (int m = 0; m < 4; ++m)
            af[m] = *(const bf16x8*)(Asl + (wrow + m * 16 + (lane & 15)) * 32 + (lane >> 4) * 8);
#pragma unroll
        for (int n = 0; n < 4; ++n)
            bfr[n] = *(const bf16x8*)(Bsl + (wcol + n * 16 + (lane & 15)) * 32 + (lane >> 4) * 8);
#pragma unroll
        for (int m = 0; m < 4; ++m)
#pragma unroll
            for (int n = 0; n < 4; ++n)
                acc[m][n] = __builtin_amdgcn_mfma_f32_16x16x32_bf16(af[m], bfr[n], acc[m][n], 0, 0, 0);
        __syncthreads();
    }

    const int r0 = (lane >> 4) * 4;
#pragma unroll
    for (int m = 0; m < 4; ++m) {
        const int grow = m0 + wrow + m * 16 + r0;
#pragma unroll
        for (int n = 0; n < 4; ++n) {
            const int gcol = n0 + wcol + n * 16 + (lane & 15);
            if (gcol < N) {
#pragma unroll
                for (int reg = 0; reg < 4; ++reg) {
                    float v = acc[m][n][reg];
                    if (RES) v += R[(size_t)(grow + reg) * N + gcol];
                    if constexpr (sizeof(OUT) == 2)
                        C[(size_t)(grow + reg) * N + gcol] = f2bf(v);
                    else
                        C[(size_t)(grow + reg) * N + gcol] = v;
                }
            }
        }
    }
}

// ---------------- dt fixup: compute the 8 dt columns exactly in fp32 -> g_dt ----------
__global__ __launch_bounds__(256) void dt_fix_kernel(const float* __restrict__ x,
                                                     const float* __restrict__ nw,
                                                     const float* __restrict__ W_in,
                                                     float* __restrict__ dt) {
    const int row  = blockIdx.x * 4 + (threadIdx.x >> 6);
    const int lane = threadIdx.x & 63;
    const float4 v = *(const float4*)(x + (size_t)row * DMODEL + lane * 4);
    float ss = v.x * v.x + v.y * v.y + v.z * v.z + v.w * v.w;
#pragma unroll
    for (int off = 1; off < 64; off <<= 1) ss += __shfl_xor(ss, off);
    const float rs = rsqrtf(ss * (1.0f / DMODEL) + 1.1920929e-7f);
    const float4 wv = *(const float4*)(nw + lane * 4);
    const float4 xn4 = make_float4(v.x * rs * wv.x, v.y * rs * wv.y,
                                   v.z * rs * wv.z, v.w * rs * wv.w);
#pragma unroll
    for (int h = 0; h < NHEADS; ++h) {
        const float4 ww = *(const float4*)(W_in + (size_t)(DPROJ - NHEADS + h) * DMODEL + lane * 4);
        float p = xn4.x * ww.x + xn4.y * ww.y + xn4.z * ww.z + xn4.w * ww.w;
#pragma unroll
        for (int off = 1; off < 64; off <<= 1) p += __shfl_xor(p, off);
        if (lane == 0) dt[(size_t)row * NHEADS + h] = p;
    }
}

// ---------------- depthwise causal conv(4) + bias + SiLU: bf16 in/out, 8 ch/thread --------
__global__ __launch_bounds__(256) void conv_silu_kernel(const short* __restrict__ zxb,
                                                        const float* __restrict__ cw,
                                                        const float* __restrict__ cb,
                                                        short* __restrict__ xbc) {
    const int idx = blockIdx.x * 256 + threadIdx.x;   // over NROWS*80
    const int c8 = (idx % 80) * 8;
    const int bl = idx / 80;
    const int l  = bl & (SEQ - 1);
    const short* src = zxb + (size_t)bl * DPROJ + DINNER + c8;

    float4 w4[8];
    float acc[8];
#pragma unroll
    for (int j = 0; j < 8; ++j) {
        w4[j] = *(const float4*)(cw + (c8 + j) * 4);
        acc[j] = cb[c8 + j];
    }
#pragma unroll
    for (int k = 0; k < 4; ++k) {
        if (l + k - 3 >= 0) {
            const bf16x8 v = *(const bf16x8*)(src + (ptrdiff_t)(k - 3) * DPROJ);
#pragma unroll
            for (int j = 0; j < 8; ++j)
                acc[j] = fmaf(bf2f(v[j]), ((const float*)&w4[j])[k], acc[j]);
        }
    }
    short8v o;
#pragma unroll
    for (int j = 0; j < 8; ++j) {
        const float s = acc[j];
        o[j] = f2bf(s / (1.f + __expf(-s)));
    }
    *(short8v*)(xbc + (size_t)bl * CONVDIM + c8) = o;
}

// ---------------- scan pass 1 (MFMA): L[p][n] = sum_t X[t][p] * (w_t * B[t][n]) ----------
__global__ __launch_bounds__(256) void chunk_state_mfma(const float* __restrict__ dt,
                                                        const short* __restrict__ xbc,
                                                        const float* __restrict__ dt_bias,
                                                        const float* __restrict__ A_log,
                                                        short* __restrict__ lstate,
                                                        float* __restrict__ decayC) {
    const int bhc = blockIdx.x;
    const int c = bhc & (NCHUNK - 1), bh = bhc >> 6, h = bh & (NHEADS - 1), b = bh >> 3;
    const int tid = threadIdx.x, lane = tid & 63, wid = tid >> 6;
    __shared__ short XT[64 * LSTR];   // XT[p][t]
    __shared__ short BT[64 * LSTR];   // (w*B)^T [n][t]
    __shared__ float wsh[CHUNK];
    const size_t row0 = (size_t)b * SEQ + (size_t)c * CHUNK;

    const float aneg  = -__expf(A_log[h]);
    const float dbias = dt_bias[h];
    if (tid < 64) {
        const float draw = dt[(row0 + tid) * NHEADS + h] + dbias;
        const float dtv  = (draw > 20.f) ? draw : log1pf(__expf(draw));
        float cum = aneg * dtv;
#pragma unroll
        for (int off = 1; off < 64; off <<= 1) {
            const float nv = __shfl_up(cum, off);
            if (lane >= off) cum += nv;
        }
        const float total = __shfl(cum, 63);
        wsh[tid] = __expf(total - cum) * dtv;
        if (tid == 63) decayC[bhc] = __expf(cum);
    }
    __syncthreads();

#pragma unroll
    for (int r = 0; r < 4; ++r) {
        const int idx  = tid + r * 256;
        const int trow = idx >> 4;
        const int c4   = (idx & 15) * 4;
        const short* rp = xbc + (row0 + trow) * CONVDIM;
        const short4 xv = *(const short4*)(rp + h * 64 + c4);
        const short4 bv = *(const short4*)(rp + DINNER + c4);
        const float w = wsh[trow];
        XT[(c4 + 0) * LSTR + trow] = xv.x;
        XT[(c4 + 1) * LSTR + trow] = xv.y;
        XT[(c4 + 2) * LSTR + trow] = xv.z;
        XT[(c4 + 3) * LSTR + trow] = xv.w;
        BT[(c4 + 0) * LSTR + trow] = f2bf(bf2f(bv.x) * w);
        BT[(c4 + 1) * LSTR + trow] = f2bf(bf2f(bv.y) * w);
        BT[(c4 + 2) * LSTR + trow] = f2bf(bf2f(bv.z) * w);
        BT[(c4 + 3) * LSTR + trow] = f2bf(bf2f(bv.w) * w);
    }
    __syncthreads();

    f32x4 acc[4];
#pragma unroll
    for (int n = 0; n < 4; ++n) acc[n] = (f32x4)0.f;
#pragma unroll
    for (int ks = 0; ks < 2; ++ks) {
        const bf16x8 af = *(const bf16x8*)(XT + (wid * 16 + (lane & 15)) * LSTR + ks * 32 + (lane >> 4) * 8);
#pragma unroll
        for (int n = 0; n < 4; ++n) {
            const bf16x8 bfv = *(const bf16x8*)(BT + (n * 16 + (lane & 15)) * LSTR + ks * 32 + (lane >> 4) * 8);
            acc[n] = __builtin_amdgcn_mfma_f32_16x16x32_bf16(af, bfv, acc[n], 0, 0, 0);
        }
    }
    short* lp = lstate + ((size_t)bhc << 12);
#pragma unroll
    for (int n = 0; n < 4; ++n)
#pragma unroll
        for (int reg = 0; reg < 4; ++reg) {
            const int p = wid * 16 + (lane >> 4) * 4 + reg;
            lp[p * 64 + n * 16 + (lane & 15)] = f2bf(acc[n][reg]);
        }
}

// ---------------- scan pass 2: inter-chunk recurrence (bf16 lstate, fp32 carry) --------
__global__ __launch_bounds__(256) void state_prefix_kernel(short* __restrict__ lstate,
                                                           const float* __restrict__ decayC) {
    const int idx = blockIdx.x * 256 + threadIdx.x;   // over BATCH*NHEADS*4096
    const int bh = idx >> 12;
    const int pn = idx & 4095;
    float S = 0.f;
    for (int c = 0; c < NCHUNK; ++c) {
        short* ptr = lstate + (((size_t)bh * NCHUNK + c) << 12) + pn;
        const float l = bf2f(*ptr);
        *ptr = f2bf(S);
        S = fmaf(S, decayC[bh * NCHUNK + c], l);
    }
}

// ---------------- scan pass 3 (MFMA): Y = mask(C@B^T)@X + exp(cum)*(C@SP^T) + Dp*X --------
__global__ __launch_bounds__(256) void chunk_scan_mfma(const float* __restrict__ dt,
                                                       const short* __restrict__ xbc,
                                                       float* __restrict__ y,
                                                       const float* __restrict__ dt_bias,
                                                       const float* __restrict__ A_log,
                                                       const float* __restrict__ Dp,
                                                       const short* __restrict__ lstate) {
    const int bhc = blockIdx.x;
    const int c = bhc & (NCHUNK - 1), bh = bhc >> 6, h = bh & (NHEADS - 1), b = bh >> 3;
    const int tid = threadIdx.x, lane = tid & 63, wid = tid >> 6;
    __shared__ short Bs[64 * LSTR];   // B rows [t][n]
    __shared__ short Cs[64 * LSTR];   // C rows [s][n]
    __shared__ short XT[64 * LSTR];   // X^T [p][t]
    __shared__ short SP[64 * LSTR];   // prefix state rows [p][n]
    __shared__ short Ms[64 * LSTR];   // masked scores rows [s][t]
    __shared__ float cums[CHUNK];
    __shared__ float dtss[CHUNK];
    const size_t row0 = (size_t)b * SEQ + (size_t)c * CHUNK;

#pragma unroll
    for (int r = 0; r < 4; ++r) {
        const int idx  = tid + r * 256;
        const int trow = idx >> 4;
        const int c4   = (idx & 15) * 4;
        const short* rp = xbc + (row0 + trow) * CONVDIM;
        const short4 xv = *(const short4*)(rp + h * 64 + c4);
        *(short4*)(Bs + trow * LSTR + c4) = *(const short4*)(rp + DINNER + c4);
        *(short4*)(Cs + trow * LSTR + c4) = *(const short4*)(rp + DINNER + DSTATE + c4);
        XT[(c4 + 0) * LSTR + trow] = xv.x;
        XT[(c4 + 1) * LSTR + trow] = xv.y;
        XT[(c4 + 2) * LSTR + trow] = xv.z;
        XT[(c4 + 3) * LSTR + trow] = xv.w;
    }
#pragma unroll
    for (int r = 0; r < 4; ++r) {
        const int idx = tid + r * 256;
        const int p = idx >> 4, n4 = (idx & 15) * 4;
        *(short4*)(SP + p * LSTR + n4) =
            *(const short4*)(lstate + ((size_t)bhc << 12) + p * 64 + n4);
    }
    const float aneg  = -__expf(A_log[h]);
    const float dbias = dt_bias[h];
    if (tid < 64) {
        const float draw = dt[(row0 + tid) * NHEADS + h] + dbias;
        const float dtv  = (draw > 20.f) ? draw : log1pf(__expf(draw));
        float cum = aneg * dtv;
#pragma unroll
        for (int off = 1; off < 64; off <<= 1) {
            const float nv = __shfl_up(cum, off);
            if (lane >= off) cum += nv;
        }
        cums[tid] = cum;
        dtss[tid] = dtv;
    }
    __syncthreads();

    // G = C @ B^T (over n)
    f32x4 accG[4];
#pragma unroll
    for (int tf = 0; tf < 4; ++tf) accG[tf] = (f32x4)0.f;
#pragma unroll
    for (int ks = 0; ks < 2; ++ks) {
        const bf16x8 af = *(const bf16x8*)(Cs + (wid * 16 + (lane & 15)) * LSTR + ks * 32 + (lane >> 4) * 8);
#pragma unroll
        for (int tf = 0; tf < 4; ++tf) {
            const bf16x8 bfv = *(const bf16x8*)(Bs + (tf * 16 + (lane & 15)) * LSTR + ks * 32 + (lane >> 4) * 8);
            accG[tf] = __builtin_amdgcn_mfma_f32_16x16x32_bf16(af, bfv, accG[tf], 0, 0, 0);
        }
    }
    // causal mask + decay scale -> Ms (bf16)
    const int srow0 = wid * 16 + (lane >> 4) * 4;
#pragma unroll
    for (int tf = 0; tf < 4; ++tf) {
        const int t = tf * 16 + (lane & 15);
        const float ct  = cums[t];
        const float dtt = dtss[t];
#pragma unroll
        for (int reg = 0; reg < 4; ++reg) {
            const int s = srow0 + reg;
            const float m = (t <= s) ? accG[tf][reg] * __expf(cums[s] - ct) * dtt : 0.f;
            Ms[s * LSTR + t] = f2bf(m);
        }
    }
    __syncthreads();

    // Y1 = M @ X ; Y2 = C @ SP^T
    f32x4 acc1[4], acc2[4];
#pragma unroll
    for (int pf = 0; pf < 4; ++pf) { acc1[pf] = (f32x4)0.f; acc2[pf] = (f32x4)0.f; }
#pragma unroll
    for (int ks = 0; ks < 2; ++ks) {
        const bf16x8 am = *(const bf16x8*)(Ms + (wid * 16 + (lane & 15)) * LSTR + ks * 32 + (lane >> 4) * 8);
        const bf16x8 ac = *(const bf16x8*)(Cs + (wid * 16 + (lane & 15)) * LSTR + ks * 32 + (lane >> 4) * 8);
#pragma unroll
        for (int pf = 0; pf < 4; ++pf) {
            const bf16x8 bx = *(const bf16x8*)(XT + (pf * 16 + (lane & 15)) * LSTR + ks * 32 + (lane >> 4) * 8);
            const bf16x8 bs = *(const bf16x8*)(SP + (pf * 16 + (lane & 15)) * LSTR + ks * 32 + (lane >> 4) * 8);
            acc1[pf] = __builtin_amdgcn_mfma_f32_16x16x32_bf16(am, bx, acc1[pf], 0, 0, 0);
            acc2[pf] = __builtin_amdgcn_mfma_f32_16x16x32_bf16(ac, bs, acc2[pf], 0, 0, 0);
        }
    }
    const float dpv = Dp[h];
    float es[4];
#pragma unroll
    for (int reg = 0; reg < 4; ++reg) es[reg] = __expf(cums[srow0 + reg]);
#pragma unroll
    for (int pf = 0; pf < 4; ++pf) {
        const int p = pf * 16 + (lane & 15);
#pragma unroll
        for (int reg = 0; reg < 4; ++reg) {
            const int s = srow0 + reg;
            const float xv = bf2f(XT[p * LSTR + s]);
            y[(row0 + s) * DINNER + h * 64 + p] =
                acc1[pf][reg] + es[reg] * acc2[pf][reg] + dpv * xv;
        }
    }
}

// ---------------- y*silu(z) -> rmsnorm (D=512) -> bf16 yzn ----------------
__global__ __launch_bounds__(256) void gate_norm_kernel(const float* __restrict__ y,
                                                        const short* __restrict__ zxb,
                                                        const float* __restrict__ gw,
                                                        short* __restrict__ yzn) {
    const int row  = blockIdx.x * 4 + (threadIdx.x >> 6);
    const int lane = threadIdx.x & 63;
    const float* yrow = y + (size_t)row * DINNER + lane * 8;
    const float4 y0 = *(const float4*)(yrow);
    const float4 y1 = *(const float4*)(yrow + 4);
    const bf16x8 zv = *(const bf16x8*)(zxb + (size_t)row * DPROJ + lane * 8);
    float v[8];
    const float yv[8] = {y0.x, y0.y, y0.z, y0.w, y1.x, y1.y, y1.z, y1.w};
#pragma unroll
    for (int i = 0; i < 8; ++i) {
        const float z = bf2f(zv[i]);
        v[i] = yv[i] * z / (1.f + __expf(-z));
    }
    float ss = 0.f;
#pragma unroll
    for (int i = 0; i < 8; ++i) ss += v[i] * v[i];
#pragma unroll
    for (int off = 1; off < 64; off <<= 1) ss += __shfl_xor(ss, off);
    const float rs = rsqrtf(ss * (1.0f / DINNER) + 1e-5f);
    const float* g = gw + lane * 8;
    short8v o;
#pragma unroll
    for (int i = 0; i < 8; ++i) o[i] = f2bf(v[i] * rs * g[i]);
    *(short8v*)(yzn + (size_t)row * DINNER + lane * 8) = o;
}

// ---------------- launch ----------------
extern "C" void kernel_launch(void* const* d_in, const int* in_sizes, int n_in,
                              void* d_out, int out_size, void* d_ws, size_t ws_size,
                              hipStream_t stream) {
    (void)in_sizes; (void)n_in; (void)out_size; (void)d_ws; (void)ws_size;
    const float* x      = (const float*)d_in[0];
    const float* W_in   = (const float*)d_in[1];
    const float* conv_w = (const float*)d_in[2];
    const float* conv_b = (const float*)d_in[3];
    const float* dt_b   = (const float*)d_in[4];
    const float* A_log  = (const float*)d_in[5];
    const float* Dp     = (const float*)d_in[6];
    const float* g_w    = (const float*)d_in[7];
    const float* n_w    = (const float*)d_in[8];
    const float* W_out  = (const float*)d_in[9];
    float* out = (float*)d_out;

    short *xn, *zxb, *xbc, *yzn, *winb, *woutb, *lst;
    float *yv, *dtv, *dcy;
    hipGetSymbolAddress((void**)&xn,    HIP_SYMBOL(g_xn));
    hipGetSymbolAddress((void**)&zxb,   HIP_SYMBOL(g_zxb));
    hipGetSymbolAddress((void**)&xbc,   HIP_SYMBOL(g_xbc));
    hipGetSymbolAddress((void**)&yv,    HIP_SYMBOL(g_y));
    hipGetSymbolAddress((void**)&dtv,   HIP_SYMBOL(g_dt));
    hipGetSymbolAddress((void**)&yzn,   HIP_SYMBOL(g_yzn));
    hipGetSymbolAddress((void**)&lst,   HIP_SYMBOL(g_lstate));
    hipGetSymbolAddress((void**)&dcy,   HIP_SYMBOL(g_decayC));
    hipGetSymbolAddress((void**)&winb,  HIP_SYMBOL(g_Winb));
    hipGetSymbolAddress((void**)&woutb, HIP_SYMBOL(g_Woutb));

    convert_bf16_kernel<<<(NPAD * DMODEL) / 256, 256, 0, stream>>>(
        W_in, winb, DPROJ * DMODEL, NPAD * DMODEL);
    convert_bf16_kernel<<<(DMODEL * DINNER) / 256, 256, 0, stream>>>(
        W_out, woutb, DMODEL * DINNER, DMODEL * DINNER);

    rmsnorm_x_kernel<<<NROWS / 4, 256, 0, stream>>>(x, n_w, xn);

    gemm_bf16_nt<false, short><<<dim3(NPAD / 128, NROWS / 128), 256, 0, stream>>>(
        xn, winb, nullptr, zxb, NROWS, DPROJ, DMODEL);

    dt_fix_kernel<<<NROWS / 4, 256, 0, stream>>>(x, n_w, W_in, dtv);

    conv_silu_kernel<<<(NROWS * 80) / 256, 256, 0, stream>>>(zxb, conv_w, conv_b, xbc);

    chunk_state_mfma<<<BATCH * NHEADS * NCHUNK, 256, 0, stream>>>(dtv, xbc, dt_b, A_log, lst, dcy);
    state_prefix_kernel<<<(BATCH * NHEADS * HEADDIM * DSTATE) / 256, 256, 0, stream>>>(lst, dcy);
    chunk_scan_mfma<<<BATCH * NHEADS * NCHUNK, 256, 0, stream>>>(dtv, xbc, yv, dt_b, A_log, Dp, lst);

    gate_norm_kernel<<<NROWS / 4, 256, 0, stream>>>(yv, zxb, g_w, yzn);

    gemm_bf16_nt<true, float><<<dim3(DMODEL / 128, NROWS / 128), 256, 0, stream>>>(
        yzn, woutb, x, out, NROWS, DMODEL, DINNER);
}

// Round 6
// 241.129 us; speedup vs baseline: 7.3308x; 1.3242x over previous
//
#include <hip/hip_runtime.h>
#include <math.h>

#define BATCH   8
#define SEQ     4096
#define DMODEL  256
#define DINNER  512
#define DSTATE  64
#define NHEADS  8
#define HEADDIM 64
#define CONVDIM 640          // DINNER + 2*DSTATE
#define DPROJ   1160         // 2*DINNER + 2*DSTATE + NHEADS
#define NROWS   (BATCH*SEQ)  // 32768
#define CHUNK   64
#define NCHUNK  (SEQ/CHUNK)  // 64
#define NPAD    1280         // DPROJ padded to mult of 128 for bf16 W_in
#define LSTR    72           // LDS row stride (shorts)

typedef short bf16x8 __attribute__((ext_vector_type(8)));
typedef short short8v __attribute__((ext_vector_type(8)));
typedef float f32x4 __attribute__((ext_vector_type(4)));

// ---- static workspace (BSS) ----
__device__ short g_xn[(size_t)NROWS * DMODEL];      // bf16 16.8 MB
__device__ short g_zxb[(size_t)NROWS * DPROJ];      // bf16 76.0 MB (z | xBC | unused dt)
__device__ short g_xbc[(size_t)NROWS * CONVDIM];    // bf16 42.0 MB (conv out; x-slice later overwritten by y)
__device__ float g_dt[(size_t)NROWS * NHEADS];      // fp32  1.0 MB (raw dt, pre-bias)
__device__ short g_yzn[(size_t)NROWS * DINNER];     // bf16 33.5 MB
__device__ short g_lstate[(size_t)BATCH * NHEADS * NCHUNK * HEADDIM * DSTATE]; // bf16 33.5 MB
__device__ float g_decayC[BATCH * NHEADS * NCHUNK];
__device__ short g_Winb[(size_t)NPAD * DMODEL];     // bf16 W_in, zero-padded rows
__device__ short g_Woutb[(size_t)DMODEL * DINNER];  // bf16 W_out

__device__ __forceinline__ short f2bf(float f) {
    unsigned u = __float_as_uint(f);
    u += 0x7fff + ((u >> 16) & 1);
    return (short)(u >> 16);
}
__device__ __forceinline__ float bf2f(short s) {
    return __uint_as_float(((unsigned)(unsigned short)s) << 16);
}

__device__ __forceinline__ void stage16(const void* gsrc, void* ldst) {
    __builtin_amdgcn_global_load_lds(
        (const __attribute__((address_space(1))) void*)gsrc,
        (__attribute__((address_space(3))) void*)ldst, 16, 0, 0);
}

// ---------------- weight convert: fp32 -> bf16 with flat zero-pad tail ----------------
__global__ __launch_bounds__(256) void convert_bf16_kernel(const float* __restrict__ src,
                                                           short* __restrict__ dst,
                                                           int n_valid, int n_total) {
    const int i = blockIdx.x * 256 + threadIdx.x;
    if (i < n_total) dst[i] = (i < n_valid) ? f2bf(src[i]) : (short)0;
}

// ---------------- rmsnorm of x (D=256) -> bf16 xn AND exact fp32 dt (8 heads) ----------
__global__ __launch_bounds__(256) void rmsnorm_dt_kernel(const float* __restrict__ x,
                                                         const float* __restrict__ w,
                                                         const float* __restrict__ W_in,
                                                         short* __restrict__ xn,
                                                         float* __restrict__ dt) {
    const int row  = blockIdx.x * 4 + (threadIdx.x >> 6);
    const int lane = threadIdx.x & 63;
    const float4 v = *(const float4*)(x + (size_t)row * DMODEL + lane * 4);
    float ss = v.x * v.x + v.y * v.y + v.z * v.z + v.w * v.w;
#pragma unroll
    for (int off = 1; off < 64; off <<= 1) ss += __shfl_xor(ss, off);
    const float rs = rsqrtf(ss * (1.0f / DMODEL) + 1.1920929e-7f);
    const float4 wv = *(const float4*)(w + lane * 4);
    const float4 xn4 = make_float4(v.x * rs * wv.x, v.y * rs * wv.y,
                                   v.z * rs * wv.z, v.w * rs * wv.w);
    short4 o;
    o.x = f2bf(xn4.x); o.y = f2bf(xn4.y); o.z = f2bf(xn4.z); o.w = f2bf(xn4.w);
    *(short4*)(xn + (size_t)row * DMODEL + lane * 4) = o;
#pragma unroll
    for (int h = 0; h < NHEADS; ++h) {
        const float4 ww = *(const float4*)(W_in + (size_t)(DPROJ - NHEADS + h) * DMODEL + lane * 4);
        float p = xn4.x * ww.x + xn4.y * ww.y + xn4.z * ww.z + xn4.w * ww.w;
#pragma unroll
        for (int off = 1; off < 64; off <<= 1) p += __shfl_xor(p, off);
        if (lane == 0) dt[(size_t)row * NHEADS + h] = p;
    }
}

// ---------------- bf16 MFMA GEMM: C[M][N] = A[M][K] * B[N][K]^T ----------
template <bool RES, typename OUT>
__global__ __launch_bounds__(256) void gemm_bf16_nt(const short* __restrict__ A,
                                                    const short* __restrict__ B,
                                                    const float* __restrict__ R,
                                                    OUT* __restrict__ C,
                                                    int M, int N, int K) {
    __shared__ __align__(16) short Asl[128 * 32];
    __shared__ __align__(16) short Bsl[128 * 32];
    const int tid  = threadIdx.x;
    const int lane = tid & 63;
    const int wid  = tid >> 6;
    const int m0 = blockIdx.y * 128, n0 = blockIdx.x * 128;
    const int wrow = (wid >> 1) * 64, wcol = (wid & 1) * 64;

    f32x4 acc[4][4];
#pragma unroll
    for (int m = 0; m < 4; ++m)
#pragma unroll
        for (int n = 0; n < 4; ++n) acc[m][n] = (f32x4)0.f;

    const int wbase = (tid & 0xC0) * 8;

    for (int k0 = 0; k0 < K; k0 += 32) {
#pragma unroll
        for (int r = 0; r < 2; ++r) {
            const int idx = r * 256 + tid;
            const int row = idx >> 2;
            const int ko  = (idx & 3) * 8;
            stage16(A + (size_t)(m0 + row) * K + k0 + ko, Asl + r * 2048 + wbase);
            stage16(B + (size_t)(n0 + row) * K + k0 + ko, Bsl + r * 2048 + wbase);
        }
        __syncthreads();
        bf16x8 af[4], bfr[4];
#pragma unroll
        for (int m = 0; m < 4; ++m)
            af[m] = *(const bf16x8*)(Asl + (wrow + m * 16 + (lane & 15)) * 32 + (lane >> 4) * 8);
#pragma unroll
        for (int n = 0; n < 4; ++n)
            bfr[n] = *(const bf16x8*)(Bsl + (wcol + n * 16 + (lane & 15)) * 32 + (lane >> 4) * 8);
#pragma unroll
        for (int m = 0; m < 4; ++m)
#pragma unroll
            for (int n = 0; n < 4; ++n)
                acc[m][n] = __builtin_amdgcn_mfma_f32_16x16x32_bf16(af[m], bfr[n], acc[m][n], 0, 0, 0);
        __syncthreads();
    }

    const int r0 = (lane >> 4) * 4;
#pragma unroll
    for (int m = 0; m < 4; ++m) {
        const int grow = m0 + wrow + m * 16 + r0;
#pragma unroll
        for (int n = 0; n < 4; ++n) {
            const int gcol = n0 + wcol + n * 16 + (lane & 15);
            if (gcol < N) {
#pragma unroll
                for (int reg = 0; reg < 4; ++reg) {
                    float v = acc[m][n][reg];
                    if (RES) v += R[(size_t)(grow + reg) * N + gcol];
                    if constexpr (sizeof(OUT) == 2)
                        C[(size_t)(grow + reg) * N + gcol] = f2bf(v);
                    else
                        C[(size_t)(grow + reg) * N + gcol] = v;
                }
            }
        }
    }
}

// ---- depthwise causal conv(4) + bias + SiLU: sliding window, 4 rows x 8 ch per thread ----
__global__ __launch_bounds__(256) void conv_silu_kernel(const short* __restrict__ zxb,
                                                        const float* __restrict__ cw,
                                                        const float* __restrict__ cb,
                                                        short* __restrict__ xbc) {
    const int idx = blockIdx.x * 256 + threadIdx.x;   // over (NROWS/4)*80
    const int c8  = (idx % 80) * 8;
    const int bl0 = (idx / 80) * 4;                   // first of 4 rows
    const int l0  = bl0 & (SEQ - 1);
    const short* src = zxb + (size_t)bl0 * DPROJ + DINNER + c8;

    float4 w4[8];
    float bias[8];
#pragma unroll
    for (int j = 0; j < 8; ++j) w4[j] = *(const float4*)(cw + (c8 + j) * 4);
    {
        const float4 b0 = *(const float4*)(cb + c8);
        const float4 b1 = *(const float4*)(cb + c8 + 4);
        bias[0] = b0.x; bias[1] = b0.y; bias[2] = b0.z; bias[3] = b0.w;
        bias[4] = b1.x; bias[5] = b1.y; bias[6] = b1.z; bias[7] = b1.w;
    }

    bf16x8 rowv[7];                                   // rows l0-3 .. l0+3
#pragma unroll
    for (int m = 0; m < 7; ++m) {
        if (l0 + m - 3 >= 0)
            rowv[m] = *(const bf16x8*)(src + (ptrdiff_t)(m - 3) * DPROJ);
        else
            rowv[m] = (bf16x8)0;
    }

#pragma unroll
    for (int r = 0; r < 4; ++r) {
        float acc[8];
#pragma unroll
        for (int j = 0; j < 8; ++j) acc[j] = bias[j];
#pragma unroll
        for (int k = 0; k < 4; ++k) {
            const bf16x8 tap = rowv[r + k];
#pragma unroll
            for (int j = 0; j < 8; ++j)
                acc[j] = fmaf(bf2f(tap[j]), ((const float*)&w4[j])[k], acc[j]);
        }
        short8v o;
#pragma unroll
        for (int j = 0; j < 8; ++j) {
            const float s = acc[j];
            o[j] = f2bf(s / (1.f + __expf(-s)));
        }
        *(short8v*)(xbc + (size_t)(bl0 + r) * CONVDIM + c8) = o;
    }
}

// ---------------- scan pass 1 (MFMA): L[p][n] = sum_t X[t][p] * (w_t * B[t][n]) ----------
__global__ __launch_bounds__(256) void chunk_state_mfma(const float* __restrict__ dt,
                                                        const short* __restrict__ xbc,
                                                        const float* __restrict__ dt_bias,
                                                        const float* __restrict__ A_log,
                                                        short* __restrict__ lstate,
                                                        float* __restrict__ decayC) {
    const int bhc = blockIdx.x;
    const int c = bhc & (NCHUNK - 1), bh = bhc >> 6, h = bh & (NHEADS - 1), b = bh >> 3;
    const int tid = threadIdx.x, lane = tid & 63, wid = tid >> 6;
    __shared__ short XT[64 * LSTR];   // XT[p][t]
    __shared__ short BT[64 * LSTR];   // (w*B)^T [n][t]
    __shared__ float wsh[CHUNK];
    const size_t row0 = (size_t)b * SEQ + (size_t)c * CHUNK;

    const float aneg  = -__expf(A_log[h]);
    const float dbias = dt_bias[h];
    if (tid < 64) {
        const float draw = dt[(row0 + tid) * NHEADS + h] + dbias;
        const float dtv  = (draw > 20.f) ? draw : log1pf(__expf(draw));
        float cum = aneg * dtv;
#pragma unroll
        for (int off = 1; off < 64; off <<= 1) {
            const float nv = __shfl_up(cum, off);
            if (lane >= off) cum += nv;
        }
        const float total = __shfl(cum, 63);
        wsh[tid] = __expf(total - cum) * dtv;
        if (tid == 63) decayC[bhc] = __expf(cum);
    }
    __syncthreads();

#pragma unroll
    for (int r = 0; r < 4; ++r) {
        const int idx  = tid + r * 256;
        const int trow = idx >> 4;
        const int c4   = (idx & 15) * 4;
        const short* rp = xbc + (row0 + trow) * CONVDIM;
        const short4 xv = *(const short4*)(rp + h * 64 + c4);
        const short4 bv = *(const short4*)(rp + DINNER + c4);
        const float w = wsh[trow];
        XT[(c4 + 0) * LSTR + trow] = xv.x;
        XT[(c4 + 1) * LSTR + trow] = xv.y;
        XT[(c4 + 2) * LSTR + trow] = xv.z;
        XT[(c4 + 3) * LSTR + trow] = xv.w;
        BT[(c4 + 0) * LSTR + trow] = f2bf(bf2f(bv.x) * w);
        BT[(c4 + 1) * LSTR + trow] = f2bf(bf2f(bv.y) * w);
        BT[(c4 + 2) * LSTR + trow] = f2bf(bf2f(bv.z) * w);
        BT[(c4 + 3) * LSTR + trow] = f2bf(bf2f(bv.w) * w);
    }
    __syncthreads();

    f32x4 acc[4];
#pragma unroll
    for (int n = 0; n < 4; ++n) acc[n] = (f32x4)0.f;
#pragma unroll
    for (int ks = 0; ks < 2; ++ks) {
        const bf16x8 af = *(const bf16x8*)(XT + (wid * 16 + (lane & 15)) * LSTR + ks * 32 + (lane >> 4) * 8);
#pragma unroll
        for (int n = 0; n < 4; ++n) {
            const bf16x8 bfv = *(const bf16x8*)(BT + (n * 16 + (lane & 15)) * LSTR + ks * 32 + (lane >> 4) * 8);
            acc[n] = __builtin_amdgcn_mfma_f32_16x16x32_bf16(af, bfv, acc[n], 0, 0, 0);
        }
    }
    short* lp = lstate + ((size_t)bhc << 12);
#pragma unroll
    for (int n = 0; n < 4; ++n)
#pragma unroll
        for (int reg = 0; reg < 4; ++reg) {
            const int p = wid * 16 + (lane >> 4) * 4 + reg;
            lp[p * 64 + n * 16 + (lane & 15)] = f2bf(acc[n][reg]);
        }
}

// ---------------- scan pass 2: inter-chunk recurrence (bf16 lstate, fp32 carry) --------
__global__ __launch_bounds__(256) void state_prefix_kernel(short* __restrict__ lstate,
                                                           const float* __restrict__ decayC) {
    const int idx = blockIdx.x * 256 + threadIdx.x;   // over BATCH*NHEADS*4096
    const int bh = idx >> 12;
    const int pn = idx & 4095;
    float S = 0.f;
    for (int c = 0; c < NCHUNK; ++c) {
        short* ptr = lstate + (((size_t)bh * NCHUNK + c) << 12) + pn;
        const float l = bf2f(*ptr);
        *ptr = f2bf(S);
        S = fmaf(S, decayC[bh * NCHUNK + c], l);
    }
}

// ---- scan pass 3 (MFMA): Y = mask(C@B^T)@X + exp(cum)*(C@SP^T) + Dp*X; y (bf16) in place over x-slice --
__global__ __launch_bounds__(256) void chunk_scan_mfma(const float* __restrict__ dt,
                                                       short* __restrict__ xbc,
                                                       const float* __restrict__ dt_bias,
                                                       const float* __restrict__ A_log,
                                                       const float* __restrict__ Dp,
                                                       const short* __restrict__ lstate) {
    const int bhc = blockIdx.x;
    const int c = bhc & (NCHUNK - 1), bh = bhc >> 6, h = bh & (NHEADS - 1), b = bh >> 3;
    const int tid = threadIdx.x, lane = tid & 63, wid = tid >> 6;
    __shared__ short Bs[64 * LSTR];   // B rows [t][n]
    __shared__ short Cs[64 * LSTR];   // C rows [s][n]
    __shared__ short XT[64 * LSTR];   // X^T [p][t]
    __shared__ short SP[64 * LSTR];   // prefix state rows [p][n]
    __shared__ short Ms[64 * LSTR];   // masked scores rows [s][t]
    __shared__ float cums[CHUNK];
    __shared__ float dtss[CHUNK];
    const size_t row0 = (size_t)b * SEQ + (size_t)c * CHUNK;

#pragma unroll
    for (int r = 0; r < 4; ++r) {
        const int idx  = tid + r * 256;
        const int trow = idx >> 4;
        const int c4   = (idx & 15) * 4;
        const short* rp = xbc + (row0 + trow) * CONVDIM;
        const short4 xv = *(const short4*)(rp + h * 64 + c4);
        *(short4*)(Bs + trow * LSTR + c4) = *(const short4*)(rp + DINNER + c4);
        *(short4*)(Cs + trow * LSTR + c4) = *(const short4*)(rp + DINNER + DSTATE + c4);
        XT[(c4 + 0) * LSTR + trow] = xv.x;
        XT[(c4 + 1) * LSTR + trow] = xv.y;
        XT[(c4 + 2) * LSTR + trow] = xv.z;
        XT[(c4 + 3) * LSTR + trow] = xv.w;
    }
#pragma unroll
    for (int r = 0; r < 4; ++r) {
        const int idx = tid + r * 256;
        const int p = idx >> 4, n4 = (idx & 15) * 4;
        *(short4*)(SP + p * LSTR + n4) =
            *(const short4*)(lstate + ((size_t)bhc << 12) + p * 64 + n4);
    }
    const float aneg  = -__expf(A_log[h]);
    const float dbias = dt_bias[h];
    if (tid < 64) {
        const float draw = dt[(row0 + tid) * NHEADS + h] + dbias;
        const float dtv  = (draw > 20.f) ? draw : log1pf(__expf(draw));
        float cum = aneg * dtv;
#pragma unroll
        for (int off = 1; off < 64; off <<= 1) {
            const float nv = __shfl_up(cum, off);
            if (lane >= off) cum += nv;
        }
        cums[tid] = cum;
        dtss[tid] = dtv;
    }
    __syncthreads();

    // G = C @ B^T (over n)
    f32x4 accG[4];
#pragma unroll
    for (int tf = 0; tf < 4; ++tf) accG[tf] = (f32x4)0.f;
#pragma unroll
    for (int ks = 0; ks < 2; ++ks) {
        const bf16x8 af = *(const bf16x8*)(Cs + (wid * 16 + (lane & 15)) * LSTR + ks * 32 + (lane >> 4) * 8);
#pragma unroll
        for (int tf = 0; tf < 4; ++tf) {
            const bf16x8 bfv = *(const bf16x8*)(Bs + (tf * 16 + (lane & 15)) * LSTR + ks * 32 + (lane >> 4) * 8);
            accG[tf] = __builtin_amdgcn_mfma_f32_16x16x32_bf16(af, bfv, accG[tf], 0, 0, 0);
        }
    }
    // causal mask + decay scale -> Ms (bf16)
    const int srow0 = wid * 16 + (lane >> 4) * 4;
#pragma unroll
    for (int tf = 0; tf < 4; ++tf) {
        const int t = tf * 16 + (lane & 15);
        const float ct  = cums[t];
        const float dtt = dtss[t];
#pragma unroll
        for (int reg = 0; reg < 4; ++reg) {
            const int s = srow0 + reg;
            const float m = (t <= s) ? accG[tf][reg] * __expf(cums[s] - ct) * dtt : 0.f;
            Ms[s * LSTR + t] = f2bf(m);
        }
    }
    __syncthreads();

    // Y1 = M @ X ; Y2 = C @ SP^T
    f32x4 acc1[4], acc2[4];
#pragma unroll
    for (int pf = 0; pf < 4; ++pf) { acc1[pf] = (f32x4)0.f; acc2[pf] = (f32x4)0.f; }
#pragma unroll
    for (int ks = 0; ks < 2; ++ks) {
        const bf16x8 am = *(const bf16x8*)(Ms + (wid * 16 + (lane & 15)) * LSTR + ks * 32 + (lane >> 4) * 8);
        const bf16x8 ac = *(const bf16x8*)(Cs + (wid * 16 + (lane & 15)) * LSTR + ks * 32 + (lane >> 4) * 8);
#pragma unroll
        for (int pf = 0; pf < 4; ++pf) {
            const bf16x8 bx = *(const bf16x8*)(XT + (pf * 16 + (lane & 15)) * LSTR + ks * 32 + (lane >> 4) * 8);
            const bf16x8 bs = *(const bf16x8*)(SP + (pf * 16 + (lane & 15)) * LSTR + ks * 32 + (lane >> 4) * 8);
            acc1[pf] = __builtin_amdgcn_mfma_f32_16x16x32_bf16(am, bx, acc1[pf], 0, 0, 0);
            acc2[pf] = __builtin_amdgcn_mfma_f32_16x16x32_bf16(ac, bs, acc2[pf], 0, 0, 0);
        }
    }
    const float dpv = Dp[h];
    float es[4];
#pragma unroll
    for (int reg = 0; reg < 4; ++reg) es[reg] = __expf(cums[srow0 + reg]);
#pragma unroll
    for (int pf = 0; pf < 4; ++pf) {
        const int p = pf * 16 + (lane & 15);
#pragma unroll
        for (int reg = 0; reg < 4; ++reg) {
            const int s = srow0 + reg;
            const float xv = bf2f(XT[p * LSTR + s]);
            xbc[(row0 + s) * CONVDIM + h * 64 + p] =
                f2bf(acc1[pf][reg] + es[reg] * acc2[pf][reg] + dpv * xv);
        }
    }
}

// ---------------- y(bf16)*silu(z) -> rmsnorm (D=512) -> bf16 yzn ----------------
__global__ __launch_bounds__(256) void gate_norm_kernel(const short* __restrict__ xbc,
                                                        const short* __restrict__ zxb,
                                                        const float* __restrict__ gw,
                                                        short* __restrict__ yzn) {
    const int row  = blockIdx.x * 4 + (threadIdx.x >> 6);
    const int lane = threadIdx.x & 63;
    const bf16x8 yv8 = *(const bf16x8*)(xbc + (size_t)row * CONVDIM + lane * 8);
    const bf16x8 zv  = *(const bf16x8*)(zxb + (size_t)row * DPROJ + lane * 8);
    float v[8];
#pragma unroll
    for (int i = 0; i < 8; ++i) {
        const float z = bf2f(zv[i]);
        v[i] = bf2f(yv8[i]) * z / (1.f + __expf(-z));
    }
    float ss = 0.f;
#pragma unroll
    for (int i = 0; i < 8; ++i) ss += v[i] * v[i];
#pragma unroll
    for (int off = 1; off < 64; off <<= 1) ss += __shfl_xor(ss, off);
    const float rs = rsqrtf(ss * (1.0f / DINNER) + 1e-5f);
    const float* g = gw + lane * 8;
    short8v o;
#pragma unroll
    for (int i = 0; i < 8; ++i) o[i] = f2bf(v[i] * rs * g[i]);
    *(short8v*)(yzn + (size_t)row * DINNER + lane * 8) = o;
}

// ---------------- launch ----------------
extern "C" void kernel_launch(void* const* d_in, const int* in_sizes, int n_in,
                              void* d_out, int out_size, void* d_ws, size_t ws_size,
                              hipStream_t stream) {
    (void)in_sizes; (void)n_in; (void)out_size; (void)d_ws; (void)ws_size;
    const float* x      = (const float*)d_in[0];
    const float* W_in   = (const float*)d_in[1];
    const float* conv_w = (const float*)d_in[2];
    const float* conv_b = (const float*)d_in[3];
    const float* dt_b   = (const float*)d_in[4];
    const float* A_log  = (const float*)d_in[5];
    const float* Dp     = (const float*)d_in[6];
    const float* g_w    = (const float*)d_in[7];
    const float* n_w    = (const float*)d_in[8];
    const float* W_out  = (const float*)d_in[9];
    float* out = (float*)d_out;

    short *xn, *zxb, *xbc, *yzn, *winb, *woutb, *lst;
    float *dtv, *dcy;
    hipGetSymbolAddress((void**)&xn,    HIP_SYMBOL(g_xn));
    hipGetSymbolAddress((void**)&zxb,   HIP_SYMBOL(g_zxb));
    hipGetSymbolAddress((void**)&xbc,   HIP_SYMBOL(g_xbc));
    hipGetSymbolAddress((void**)&dtv,   HIP_SYMBOL(g_dt));
    hipGetSymbolAddress((void**)&yzn,   HIP_SYMBOL(g_yzn));
    hipGetSymbolAddress((void**)&lst,   HIP_SYMBOL(g_lstate));
    hipGetSymbolAddress((void**)&dcy,   HIP_SYMBOL(g_decayC));
    hipGetSymbolAddress((void**)&winb,  HIP_SYMBOL(g_Winb));
    hipGetSymbolAddress((void**)&woutb, HIP_SYMBOL(g_Woutb));

    convert_bf16_kernel<<<(NPAD * DMODEL) / 256, 256, 0, stream>>>(
        W_in, winb, DPROJ * DMODEL, NPAD * DMODEL);
    convert_bf16_kernel<<<(DMODEL * DINNER) / 256, 256, 0, stream>>>(
        W_out, woutb, DMODEL * DINNER, DMODEL * DINNER);

    rmsnorm_dt_kernel<<<NROWS / 4, 256, 0, stream>>>(x, n_w, W_in, xn, dtv);

    gemm_bf16_nt<false, short><<<dim3(NPAD / 128, NROWS / 128), 256, 0, stream>>>(
        xn, winb, nullptr, zxb, NROWS, DPROJ, DMODEL);

    conv_silu_kernel<<<(NROWS / 4 * 80) / 256, 256, 0, stream>>>(zxb, conv_w, conv_b, xbc);

    chunk_state_mfma<<<BATCH * NHEADS * NCHUNK, 256, 0, stream>>>(dtv, xbc, dt_b, A_log, lst, dcy);
    state_prefix_kernel<<<(BATCH * NHEADS * HEADDIM * DSTATE) / 256, 256, 0, stream>>>(lst, dcy);
    chunk_scan_mfma<<<BATCH * NHEADS * NCHUNK, 256, 0, stream>>>(dtv, xbc, dt_b, A_log, Dp, lst);

    gate_norm_kernel<<<NROWS / 4, 256, 0, stream>>>(xbc, zxb, g_w, yzn);

    gemm_bf16_nt<true, float><<<dim3(DMODEL / 128, NROWS / 128), 256, 0, stream>>>(
        yzn, woutb, x, out, NROWS, DMODEL, DINNER);
}

// Round 7
// 216.461 us; speedup vs baseline: 8.1663x; 1.1140x over previous
//
#include <hip/hip_runtime.h>
#include <math.h>

#define BATCH   8
#define SEQ     4096
#define DMODEL  256
#define DINNER  512
#define DSTATE  64
#define NHEADS  8
#define HEADDIM 64
#define CONVDIM 640          // DINNER + 2*DSTATE
#define DPROJ   1160         // 2*DINNER + 2*DSTATE + NHEADS
#define NROWS   (BATCH*SEQ)  // 32768
#define CHUNK   64
#define NCHUNK  (SEQ/CHUNK)  // 64
#define NPAD    1280         // DPROJ padded to mult of 128 for bf16 W_in
#define LSTR    72           // LDS row stride (shorts)

typedef short bf16x8 __attribute__((ext_vector_type(8)));
typedef short short8v __attribute__((ext_vector_type(8)));
typedef float f32x4 __attribute__((ext_vector_type(4)));

// ---- static workspace (BSS) ----
__device__ short g_xn[(size_t)NROWS * DMODEL];      // bf16 16.8 MB
__device__ short g_zxb[(size_t)NROWS * DPROJ];      // bf16 76.0 MB (z | xBC | unused dt)
__device__ short g_xbc[(size_t)NROWS * CONVDIM];    // bf16 42.0 MB (conv out; x-slice later overwritten by y)
__device__ float g_dt[(size_t)NROWS * NHEADS];      // fp32  1.0 MB (raw dt, pre-bias)
__device__ short g_yzn[(size_t)NROWS * DINNER];     // bf16 33.5 MB
__device__ short g_lstate[(size_t)BATCH * NHEADS * NCHUNK * HEADDIM * DSTATE]; // bf16 33.5 MB
__device__ float g_decayC[BATCH * NHEADS * NCHUNK];
__device__ short g_Winb[(size_t)NPAD * DMODEL];     // bf16 W_in, zero-padded rows
__device__ short g_Woutb[(size_t)DMODEL * DINNER];  // bf16 W_out

__device__ __forceinline__ short f2bf(float f) {
    unsigned u = __float_as_uint(f);
    u += 0x7fff + ((u >> 16) & 1);
    return (short)(u >> 16);
}
__device__ __forceinline__ float bf2f(short s) {
    return __uint_as_float(((unsigned)(unsigned short)s) << 16);
}

__device__ __forceinline__ void stage16(const void* gsrc, void* ldst) {
    __builtin_amdgcn_global_load_lds(
        (const __attribute__((address_space(1))) void*)gsrc,
        (__attribute__((address_space(3))) void*)ldst, 16, 0, 0);
}

// ---------------- weight convert: fp32 -> bf16 with flat zero-pad tail ----------------
__global__ __launch_bounds__(256) void convert_bf16_kernel(const float* __restrict__ src,
                                                           short* __restrict__ dst,
                                                           int n_valid, int n_total) {
    const int i = blockIdx.x * 256 + threadIdx.x;
    if (i < n_total) dst[i] = (i < n_valid) ? f2bf(src[i]) : (short)0;
}

// ---------------- rmsnorm of x (D=256) -> bf16 xn AND exact fp32 dt (8 heads) ----------
__global__ __launch_bounds__(256) void rmsnorm_dt_kernel(const float* __restrict__ x,
                                                         const float* __restrict__ w,
                                                         const float* __restrict__ W_in,
                                                         short* __restrict__ xn,
                                                         float* __restrict__ dt) {
    const int row  = blockIdx.x * 4 + (threadIdx.x >> 6);
    const int lane = threadIdx.x & 63;
    const float4 v = *(const float4*)(x + (size_t)row * DMODEL + lane * 4);
    float ss = v.x * v.x + v.y * v.y + v.z * v.z + v.w * v.w;
#pragma unroll
    for (int off = 1; off < 64; off <<= 1) ss += __shfl_xor(ss, off);
    const float rs = rsqrtf(ss * (1.0f / DMODEL) + 1.1920929e-7f);
    const float4 wv = *(const float4*)(w + lane * 4);
    const float4 xn4 = make_float4(v.x * rs * wv.x, v.y * rs * wv.y,
                                   v.z * rs * wv.z, v.w * rs * wv.w);
    short4 o;
    o.x = f2bf(xn4.x); o.y = f2bf(xn4.y); o.z = f2bf(xn4.z); o.w = f2bf(xn4.w);
    *(short4*)(xn + (size_t)row * DMODEL + lane * 4) = o;
#pragma unroll
    for (int h = 0; h < NHEADS; ++h) {
        const float4 ww = *(const float4*)(W_in + (size_t)(DPROJ - NHEADS + h) * DMODEL + lane * 4);
        float p = xn4.x * ww.x + xn4.y * ww.y + xn4.z * ww.z + xn4.w * ww.w;
#pragma unroll
        for (int off = 1; off < 64; off <<= 1) p += __shfl_xor(p, off);
        if (lane == 0) dt[(size_t)row * NHEADS + h] = p;
    }
}

// ---------------- bf16 MFMA GEMM: C[M][N] = A[M][K] * B[N][K]^T ----------
// 1-D grid = NX * (M/128). XCD-chunked swizzle: all NX n-blocks of an m-strip
// map to the same XCD (same L%8) and adjacent dispatch slots -> A strip stays
// in that XCD's L2 instead of being fetched by all 8 XCDs.
template <bool RES, typename OUT>
__global__ __launch_bounds__(256) void gemm_bf16_nt(const short* __restrict__ A,
                                                    const short* __restrict__ B,
                                                    const float* __restrict__ R,
                                                    OUT* __restrict__ C,
                                                    int NX, int M, int N, int K) {
    const int L   = blockIdx.x;
    const int xcd = L & 7;
    const int r   = L >> 3;
    const int mstrips_per_xcd = (M / 128) >> 3;
    const int mblk = xcd * mstrips_per_xcd + r / NX;
    const int nblk = r % NX;
    const int m0 = mblk * 128, n0 = nblk * 128;

    __shared__ __align__(16) short Asl[128 * 32];
    __shared__ __align__(16) short Bsl[128 * 32];
    const int tid  = threadIdx.x;
    const int lane = tid & 63;
    const int wid  = tid >> 6;
    const int wrow = (wid >> 1) * 64, wcol = (wid & 1) * 64;

    f32x4 acc[4][4];
#pragma unroll
    for (int m = 0; m < 4; ++m)
#pragma unroll
        for (int n = 0; n < 4; ++n) acc[m][n] = (f32x4)0.f;

    const int wbase = (tid & 0xC0) * 8;

    for (int k0 = 0; k0 < K; k0 += 32) {
#pragma unroll
        for (int rr = 0; rr < 2; ++rr) {
            const int idx = rr * 256 + tid;
            const int row = idx >> 2;
            const int ko  = (idx & 3) * 8;
            stage16(A + (size_t)(m0 + row) * K + k0 + ko, Asl + rr * 2048 + wbase);
            stage16(B + (size_t)(n0 + row) * K + k0 + ko, Bsl + rr * 2048 + wbase);
        }
        __syncthreads();
        bf16x8 af[4], bfr[4];
#pragma unroll
        for (int m = 0; m < 4; ++m)
            af[m] = *(const bf16x8*)(Asl + (wrow + m * 16 + (lane & 15)) * 32 + (lane >> 4) * 8);
#pragma unroll
        for (int n = 0; n < 4; ++n)
            bfr[n] = *(const bf16x8*)(Bsl + (wcol + n * 16 + (lane & 15)) * 32 + (lane >> 4) * 8);
#pragma unroll
        for (int m = 0; m < 4; ++m)
#pragma unroll
            for (int n = 0; n < 4; ++n)
                acc[m][n] = __builtin_amdgcn_mfma_f32_16x16x32_bf16(af[m], bfr[n], acc[m][n], 0, 0, 0);
        __syncthreads();
    }

    const int r0 = (lane >> 4) * 4;
#pragma unroll
    for (int m = 0; m < 4; ++m) {
        const int grow = m0 + wrow + m * 16 + r0;
#pragma unroll
        for (int n = 0; n < 4; ++n) {
            const int gcol = n0 + wcol + n * 16 + (lane & 15);
            if (gcol < N) {
#pragma unroll
                for (int reg = 0; reg < 4; ++reg) {
                    float v = acc[m][n][reg];
                    if (RES) v += R[(size_t)(grow + reg) * N + gcol];
                    if constexpr (sizeof(OUT) == 2)
                        C[(size_t)(grow + reg) * N + gcol] = f2bf(v);
                    else
                        C[(size_t)(grow + reg) * N + gcol] = v;
                }
            }
        }
    }
}

// ---- depthwise causal conv(4) + bias + SiLU: sliding window, 4 rows x 8 ch per thread ----
__global__ __launch_bounds__(256) void conv_silu_kernel(const short* __restrict__ zxb,
                                                        const float* __restrict__ cw,
                                                        const float* __restrict__ cb,
                                                        short* __restrict__ xbc) {
    const int idx = blockIdx.x * 256 + threadIdx.x;   // over (NROWS/4)*80
    const int c8  = (idx % 80) * 8;
    const int bl0 = (idx / 80) * 4;                   // first of 4 rows
    const int l0  = bl0 & (SEQ - 1);
    const short* src = zxb + (size_t)bl0 * DPROJ + DINNER + c8;

    float4 w4[8];
    float bias[8];
#pragma unroll
    for (int j = 0; j < 8; ++j) w4[j] = *(const float4*)(cw + (c8 + j) * 4);
    {
        const float4 b0 = *(const float4*)(cb + c8);
        const float4 b1 = *(const float4*)(cb + c8 + 4);
        bias[0] = b0.x; bias[1] = b0.y; bias[2] = b0.z; bias[3] = b0.w;
        bias[4] = b1.x; bias[5] = b1.y; bias[6] = b1.z; bias[7] = b1.w;
    }

    bf16x8 rowv[7];                                   // rows l0-3 .. l0+3
#pragma unroll
    for (int m = 0; m < 7; ++m) {
        if (l0 + m - 3 >= 0)
            rowv[m] = *(const bf16x8*)(src + (ptrdiff_t)(m - 3) * DPROJ);
        else
            rowv[m] = (bf16x8)0;
    }

#pragma unroll
    for (int r = 0; r < 4; ++r) {
        float acc[8];
#pragma unroll
        for (int j = 0; j < 8; ++j) acc[j] = bias[j];
#pragma unroll
        for (int k = 0; k < 4; ++k) {
            const bf16x8 tap = rowv[r + k];
#pragma unroll
            for (int j = 0; j < 8; ++j)
                acc[j] = fmaf(bf2f(tap[j]), ((const float*)&w4[j])[k], acc[j]);
        }
        short8v o;
#pragma unroll
        for (int j = 0; j < 8; ++j) {
            const float s = acc[j];
            o[j] = f2bf(s / (1.f + __expf(-s)));
        }
        *(short8v*)(xbc + (size_t)(bl0 + r) * CONVDIM + c8) = o;
    }
}

// ---------------- scan pass 1 (MFMA): L[p][n] = sum_t X[t][p] * (w_t * B[t][n]) ----------
__global__ __launch_bounds__(256) void chunk_state_mfma(const float* __restrict__ dt,
                                                        const short* __restrict__ xbc,
                                                        const float* __restrict__ dt_bias,
                                                        const float* __restrict__ A_log,
                                                        short* __restrict__ lstate,
                                                        float* __restrict__ decayC) {
    const int bhc = blockIdx.x;
    const int c = bhc & (NCHUNK - 1), bh = bhc >> 6, h = bh & (NHEADS - 1), b = bh >> 3;
    const int tid = threadIdx.x, lane = tid & 63, wid = tid >> 6;
    __shared__ short XT[64 * LSTR];   // XT[p][t]
    __shared__ short BT[64 * LSTR];   // (w*B)^T [n][t]
    __shared__ float wsh[CHUNK];
    const size_t row0 = (size_t)b * SEQ + (size_t)c * CHUNK;

    const float aneg  = -__expf(A_log[h]);
    const float dbias = dt_bias[h];
    if (tid < 64) {
        const float draw = dt[(row0 + tid) * NHEADS + h] + dbias;
        const float dtv  = (draw > 20.f) ? draw : log1pf(__expf(draw));
        float cum = aneg * dtv;
#pragma unroll
        for (int off = 1; off < 64; off <<= 1) {
            const float nv = __shfl_up(cum, off);
            if (lane >= off) cum += nv;
        }
        const float total = __shfl(cum, 63);
        wsh[tid] = __expf(total - cum) * dtv;
        if (tid == 63) decayC[bhc] = __expf(cum);
    }
    __syncthreads();

#pragma unroll
    for (int r = 0; r < 4; ++r) {
        const int idx  = tid + r * 256;
        const int trow = idx >> 4;
        const int c4   = (idx & 15) * 4;
        const short* rp = xbc + (row0 + trow) * CONVDIM;
        const short4 xv = *(const short4*)(rp + h * 64 + c4);
        const short4 bv = *(const short4*)(rp + DINNER + c4);
        const float w = wsh[trow];
        XT[(c4 + 0) * LSTR + trow] = xv.x;
        XT[(c4 + 1) * LSTR + trow] = xv.y;
        XT[(c4 + 2) * LSTR + trow] = xv.z;
        XT[(c4 + 3) * LSTR + trow] = xv.w;
        BT[(c4 + 0) * LSTR + trow] = f2bf(bf2f(bv.x) * w);
        BT[(c4 + 1) * LSTR + trow] = f2bf(bf2f(bv.y) * w);
        BT[(c4 + 2) * LSTR + trow] = f2bf(bf2f(bv.z) * w);
        BT[(c4 + 3) * LSTR + trow] = f2bf(bf2f(bv.w) * w);
    }
    __syncthreads();

    f32x4 acc[4];
#pragma unroll
    for (int n = 0; n < 4; ++n) acc[n] = (f32x4)0.f;
#pragma unroll
    for (int ks = 0; ks < 2; ++ks) {
        const bf16x8 af = *(const bf16x8*)(XT + (wid * 16 + (lane & 15)) * LSTR + ks * 32 + (lane >> 4) * 8);
#pragma unroll
        for (int n = 0; n < 4; ++n) {
            const bf16x8 bfv = *(const bf16x8*)(BT + (n * 16 + (lane & 15)) * LSTR + ks * 32 + (lane >> 4) * 8);
            acc[n] = __builtin_amdgcn_mfma_f32_16x16x32_bf16(af, bfv, acc[n], 0, 0, 0);
        }
    }
    short* lp = lstate + ((size_t)bhc << 12);
#pragma unroll
    for (int n = 0; n < 4; ++n)
#pragma unroll
        for (int reg = 0; reg < 4; ++reg) {
            const int p = wid * 16 + (lane >> 4) * 4 + reg;
            lp[p * 64 + n * 16 + (lane & 15)] = f2bf(acc[n][reg]);
        }
}

// ---------------- scan pass 2: inter-chunk recurrence (bf16 lstate, fp32 carry) --------
__global__ __launch_bounds__(256) void state_prefix_kernel(short* __restrict__ lstate,
                                                           const float* __restrict__ decayC) {
    const int idx = blockIdx.x * 256 + threadIdx.x;   // over BATCH*NHEADS*4096
    const int bh = idx >> 12;
    const int pn = idx & 4095;
    float S = 0.f;
    for (int c = 0; c < NCHUNK; ++c) {
        short* ptr = lstate + (((size_t)bh * NCHUNK + c) << 12) + pn;
        const float l = bf2f(*ptr);
        *ptr = f2bf(S);
        S = fmaf(S, decayC[bh * NCHUNK + c], l);
    }
}

// ---- scan pass 3 (MFMA): Y = mask(C@B^T)@X + exp(cum)*(C@SP^T) + Dp*X; y (bf16) in place --
__global__ __launch_bounds__(256) void chunk_scan_mfma(const float* __restrict__ dt,
                                                       short* __restrict__ xbc,
                                                       const float* __restrict__ dt_bias,
                                                       const float* __restrict__ A_log,
                                                       const float* __restrict__ Dp,
                                                       const short* __restrict__ lstate) {
    const int bhc = blockIdx.x;
    const int c = bhc & (NCHUNK - 1), bh = bhc >> 6, h = bh & (NHEADS - 1), b = bh >> 3;
    const int tid = threadIdx.x, lane = tid & 63, wid = tid >> 6;
    __shared__ short Bs[64 * LSTR];   // B rows [t][n]
    __shared__ short Cs[64 * LSTR];   // C rows [s][n]
    __shared__ short XT[64 * LSTR];   // X^T [p][t]
    __shared__ short SP[64 * LSTR];   // prefix state rows [p][n]
    __shared__ short Ms[64 * LSTR];   // masked scores rows [s][t]
    __shared__ float cums[CHUNK];
    __shared__ float dtss[CHUNK];
    const size_t row0 = (size_t)b * SEQ + (size_t)c * CHUNK;

#pragma unroll
    for (int r = 0; r < 4; ++r) {
        const int idx  = tid + r * 256;
        const int trow = idx >> 4;
        const int c4   = (idx & 15) * 4;
        const short* rp = xbc + (row0 + trow) * CONVDIM;
        const short4 xv = *(const short4*)(rp + h * 64 + c4);
        *(short4*)(Bs + trow * LSTR + c4) = *(const short4*)(rp + DINNER + c4);
        *(short4*)(Cs + trow * LSTR + c4) = *(const short4*)(rp + DINNER + DSTATE + c4);
        XT[(c4 + 0) * LSTR + trow] = xv.x;
        XT[(c4 + 1) * LSTR + trow] = xv.y;
        XT[(c4 + 2) * LSTR + trow] = xv.z;
        XT[(c4 + 3) * LSTR + trow] = xv.w;
    }
#pragma unroll
    for (int r = 0; r < 4; ++r) {
        const int idx = tid + r * 256;
        const int p = idx >> 4, n4 = (idx & 15) * 4;
        *(short4*)(SP + p * LSTR + n4) =
            *(const short4*)(lstate + ((size_t)bhc << 12) + p * 64 + n4);
    }
    const float aneg  = -__expf(A_log[h]);
    const float dbias = dt_bias[h];
    if (tid < 64) {
        const float draw = dt[(row0 + tid) * NHEADS + h] + dbias;
        const float dtv  = (draw > 20.f) ? draw : log1pf(__expf(draw));
        float cum = aneg * dtv;
#pragma unroll
        for (int off = 1; off < 64; off <<= 1) {
            const float nv = __shfl_up(cum, off);
            if (lane >= off) cum += nv;
        }
        cums[tid] = cum;
        dtss[tid] = dtv;
    }
    __syncthreads();

    // G = C @ B^T (over n)
    f32x4 accG[4];
#pragma unroll
    for (int tf = 0; tf < 4; ++tf) accG[tf] = (f32x4)0.f;
#pragma unroll
    for (int ks = 0; ks < 2; ++ks) {
        const bf16x8 af = *(const bf16x8*)(Cs + (wid * 16 + (lane & 15)) * LSTR + ks * 32 + (lane >> 4) * 8);
#pragma unroll
        for (int tf = 0; tf < 4; ++tf) {
            const bf16x8 bfv = *(const bf16x8*)(Bs + (tf * 16 + (lane & 15)) * LSTR + ks * 32 + (lane >> 4) * 8);
            accG[tf] = __builtin_amdgcn_mfma_f32_16x16x32_bf16(af, bfv, accG[tf], 0, 0, 0);
        }
    }
    // causal mask + decay scale -> Ms (bf16)
    const int srow0 = wid * 16 + (lane >> 4) * 4;
#pragma unroll
    for (int tf = 0; tf < 4; ++tf) {
        const int t = tf * 16 + (lane & 15);
        const float ct  = cums[t];
        const float dtt = dtss[t];
#pragma unroll
        for (int reg = 0; reg < 4; ++reg) {
            const int s = srow0 + reg;
            const float m = (t <= s) ? accG[tf][reg] * __expf(cums[s] - ct) * dtt : 0.f;
            Ms[s * LSTR + t] = f2bf(m);
        }
    }
    __syncthreads();

    // Y1 = M @ X ; Y2 = C @ SP^T
    f32x4 acc1[4], acc2[4];
#pragma unroll
    for (int pf = 0; pf < 4; ++pf) { acc1[pf] = (f32x4)0.f; acc2[pf] = (f32x4)0.f; }
#pragma unroll
    for (int ks = 0; ks < 2; ++ks) {
        const bf16x8 am = *(const bf16x8*)(Ms + (wid * 16 + (lane & 15)) * LSTR + ks * 32 + (lane >> 4) * 8);
        const bf16x8 ac = *(const bf16x8*)(Cs + (wid * 16 + (lane & 15)) * LSTR + ks * 32 + (lane >> 4) * 8);
#pragma unroll
        for (int pf = 0; pf < 4; ++pf) {
            const bf16x8 bx = *(const bf16x8*)(XT + (pf * 16 + (lane & 15)) * LSTR + ks * 32 + (lane >> 4) * 8);
            const bf16x8 bs = *(const bf16x8*)(SP + (pf * 16 + (lane & 15)) * LSTR + ks * 32 + (lane >> 4) * 8);
            acc1[pf] = __builtin_amdgcn_mfma_f32_16x16x32_bf16(am, bx, acc1[pf], 0, 0, 0);
            acc2[pf] = __builtin_amdgcn_mfma_f32_16x16x32_bf16(ac, bs, acc2[pf], 0, 0, 0);
        }
    }
    const float dpv = Dp[h];
    float es[4];
#pragma unroll
    for (int reg = 0; reg < 4; ++reg) es[reg] = __expf(cums[srow0 + reg]);
#pragma unroll
    for (int pf = 0; pf < 4; ++pf) {
        const int p = pf * 16 + (lane & 15);
#pragma unroll
        for (int reg = 0; reg < 4; ++reg) {
            const int s = srow0 + reg;
            const float xv = bf2f(XT[p * LSTR + s]);
            xbc[(row0 + s) * CONVDIM + h * 64 + p] =
                f2bf(acc1[pf][reg] + es[reg] * acc2[pf][reg] + dpv * xv);
        }
    }
}

// ---------------- y(bf16)*silu(z) -> rmsnorm (D=512) -> bf16 yzn ----------------
__global__ __launch_bounds__(256) void gate_norm_kernel(const short* __restrict__ xbc,
                                                        const short* __restrict__ zxb,
                                                        const float* __restrict__ gw,
                                                        short* __restrict__ yzn) {
    const int row  = blockIdx.x * 4 + (threadIdx.x >> 6);
    const int lane = threadIdx.x & 63;
    const bf16x8 yv8 = *(const bf16x8*)(xbc + (size_t)row * CONVDIM + lane * 8);
    const bf16x8 zv  = *(const bf16x8*)(zxb + (size_t)row * DPROJ + lane * 8);
    float v[8];
#pragma unroll
    for (int i = 0; i < 8; ++i) {
        const float z = bf2f(zv[i]);
        v[i] = bf2f(yv8[i]) * z / (1.f + __expf(-z));
    }
    float ss = 0.f;
#pragma unroll
    for (int i = 0; i < 8; ++i) ss += v[i] * v[i];
#pragma unroll
    for (int off = 1; off < 64; off <<= 1) ss += __shfl_xor(ss, off);
    const float rs = rsqrtf(ss * (1.0f / DINNER) + 1e-5f);
    const float* g = gw + lane * 8;
    short8v o;
#pragma unroll
    for (int i = 0; i < 8; ++i) o[i] = f2bf(v[i] * rs * g[i]);
    *(short8v*)(yzn + (size_t)row * DINNER + lane * 8) = o;
}

// ---------------- launch ----------------
extern "C" void kernel_launch(void* const* d_in, const int* in_sizes, int n_in,
                              void* d_out, int out_size, void* d_ws, size_t ws_size,
                              hipStream_t stream) {
    (void)in_sizes; (void)n_in; (void)out_size; (void)d_ws; (void)ws_size;
    const float* x      = (const float*)d_in[0];
    const float* W_in   = (const float*)d_in[1];
    const float* conv_w = (const float*)d_in[2];
    const float* conv_b = (const float*)d_in[3];
    const float* dt_b   = (const float*)d_in[4];
    const float* A_log  = (const float*)d_in[5];
    const float* Dp     = (const float*)d_in[6];
    const float* g_w    = (const float*)d_in[7];
    const float* n_w    = (const float*)d_in[8];
    const float* W_out  = (const float*)d_in[9];
    float* out = (float*)d_out;

    short *xn, *zxb, *xbc, *yzn, *winb, *woutb, *lst;
    float *dtv, *dcy;
    hipGetSymbolAddress((void**)&xn,    HIP_SYMBOL(g_xn));
    hipGetSymbolAddress((void**)&zxb,   HIP_SYMBOL(g_zxb));
    hipGetSymbolAddress((void**)&xbc,   HIP_SYMBOL(g_xbc));
    hipGetSymbolAddress((void**)&dtv,   HIP_SYMBOL(g_dt));
    hipGetSymbolAddress((void**)&yzn,   HIP_SYMBOL(g_yzn));
    hipGetSymbolAddress((void**)&lst,   HIP_SYMBOL(g_lstate));
    hipGetSymbolAddress((void**)&dcy,   HIP_SYMBOL(g_decayC));
    hipGetSymbolAddress((void**)&winb,  HIP_SYMBOL(g_Winb));
    hipGetSymbolAddress((void**)&woutb, HIP_SYMBOL(g_Woutb));

    convert_bf16_kernel<<<(NPAD * DMODEL) / 256, 256, 0, stream>>>(
        W_in, winb, DPROJ * DMODEL, NPAD * DMODEL);
    convert_bf16_kernel<<<(DMODEL * DINNER) / 256, 256, 0, stream>>>(
        W_out, woutb, DMODEL * DINNER, DMODEL * DINNER);

    rmsnorm_dt_kernel<<<NROWS / 4, 256, 0, stream>>>(x, n_w, W_in, xn, dtv);

    gemm_bf16_nt<false, short><<<(NPAD / 128) * (NROWS / 128), 256, 0, stream>>>(
        xn, winb, nullptr, zxb, NPAD / 128, NROWS, DPROJ, DMODEL);

    conv_silu_kernel<<<(NROWS / 4 * 80) / 256, 256, 0, stream>>>(zxb, conv_w, conv_b, xbc);

    chunk_state_mfma<<<BATCH * NHEADS * NCHUNK, 256, 0, stream>>>(dtv, xbc, dt_b, A_log, lst, dcy);
    state_prefix_kernel<<<(BATCH * NHEADS * HEADDIM * DSTATE) / 256, 256, 0, stream>>>(lst, dcy);
    chunk_scan_mfma<<<BATCH * NHEADS * NCHUNK, 256, 0, stream>>>(dtv, xbc, dt_b, A_log, Dp, lst);

    gate_norm_kernel<<<NROWS / 4, 256, 0, stream>>>(xbc, zxb, g_w, yzn);

    gemm_bf16_nt<true, float><<<(DMODEL / 128) * (NROWS / 128), 256, 0, stream>>>(
        yzn, woutb, x, out, DMODEL / 128, NROWS, DMODEL, DINNER);
}